// Round 1
// baseline (644.008 us; speedup 1.0000x reference)
//
#include <hip/hip_runtime.h>

#define DEVI __device__ __forceinline__

using u16 = unsigned short;
using u32 = unsigned int;

typedef __attribute__((ext_vector_type(8))) short short8v;
typedef __attribute__((ext_vector_type(4))) float f32x4;

DEVI u16 f2b(float f) {
  u32 u = __builtin_bit_cast(u32, f);
  u += 0x7fffu + ((u >> 16) & 1u);
  return (u16)(u >> 16);
}
DEVI float b2f(u16 b) { return __builtin_bit_cast(float, (u32)b << 16); }

DEVI void gload16(const void* g, void* l) {
  __builtin_amdgcn_global_load_lds(
      (const __attribute__((address_space(1))) void*)g,
      (__attribute__((address_space(3))) void*)l, 16, 0, 0);
}

// ---------------- x: fp32 -> bf16 ----------------
__global__ __launch_bounds__(256) void cvt_x_k(const float* __restrict__ in,
                                               u16* __restrict__ out) {
  size_t i = ((size_t)blockIdx.x * 256 + threadIdx.x) * 8;
  f32x4 a = *(const f32x4*)(in + i);
  f32x4 c = *(const f32x4*)(in + i + 4);
  short8v o;
  o[0] = (short)f2b(a[0]); o[1] = (short)f2b(a[1]);
  o[2] = (short)f2b(a[2]); o[3] = (short)f2b(a[3]);
  o[4] = (short)f2b(c[0]); o[5] = (short)f2b(c[1]);
  o[6] = (short)f2b(c[2]); o[7] = (short)f2b(c[3]);
  *(short8v*)(out + i) = o;
}

// ---------------- transpose + cvt: out[c][r] = bf16(in[r][c]) ----------------
__global__ __launch_bounds__(256) void transpose_cvt_k(
    const float* __restrict__ in, u16* __restrict__ out, int R, int Ccols) {
  __shared__ u16 tile[64][65];
  const int r0 = blockIdx.y * 64, c0 = blockIdx.x * 64;
  const int tx = threadIdx.x & 63, ty = threadIdx.x >> 6;
#pragma unroll
  for (int jj = 0; jj < 16; ++jj) {
    int r = ty + jj * 4;
    tile[r][tx] = f2b(in[(size_t)(r0 + r) * Ccols + c0 + tx]);
  }
  __syncthreads();
#pragma unroll
  for (int jj = 0; jj < 16; ++jj) {
    int c = ty + jj * 4;
    out[(size_t)(c0 + c) * R + r0 + tx] = tile[tx][c];
  }
}

// ---------------- rope table: cos/sin[s][i], i in [0,64) ----------------
__global__ __launch_bounds__(256) void rope_table_k(float* __restrict__ cosT,
                                                    float* __restrict__ sinT) {
  int idx = blockIdx.x * 256 + threadIdx.x;
  int s = idx >> 6, i = idx & 63;
  // inv_freq = 10000^(-i/64) = exp(-(i/64)*ln(10000))
  float inv_freq = expf(-(float)i * (1.0f / 64.0f) * 9.210340371976184f);
  float ang = (float)s * inv_freq;
  cosT[idx] = cosf(ang);
  sinT[idx] = sinf(ang);
}

// ---------------- rope + scatter q,k ----------------
// qkv [B*S][3072] bf16. q cols [0,2048), k cols [2048,2560).
// q_r [b][h][s][128], k_r [b][kh][s][128]
__global__ __launch_bounds__(256) void rope_scatter_k(
    const u16* __restrict__ qkv, const float* __restrict__ cosT,
    const float* __restrict__ sinT, u16* __restrict__ q_r,
    u16* __restrict__ k_r) {
  const int row = blockIdx.x;
  const int b = row >> 11, s = row & 2047;
  const u16* in = qkv + (size_t)row * 3072;
  const float* cp = cosT + s * 64;
  const float* sp = sinT + s * 64;
  for (int p = threadIdx.x; p < 1280; p += 256) {
    int f0 = p * 2;
    u32 pair = *(const u32*)(in + f0);
    float x0 = b2f((u16)(pair & 0xffffu));
    float x1 = b2f((u16)(pair >> 16));
    int d, head;
    u16* dst;
    if (f0 < 2048) {
      head = f0 >> 7; d = f0 & 127;
      dst = q_r + (((size_t)(b * 16 + head)) * 2048 + s) * 128 + d;
    } else {
      int idx = f0 - 2048;
      head = idx >> 7; d = idx & 127;
      dst = k_r + (((size_t)(b * 4 + head)) * 2048 + s) * 128 + d;
    }
    int i = d >> 1;
    float c = cp[i], sn = sp[i];
    float o0 = x0 * c - x1 * sn;
    float o1 = x0 * sn + x1 * c;
    *(u32*)dst = (u32)f2b(o0) | ((u32)f2b(o1) << 16);
  }
}

// ---------------- v transpose: vT[b][kh][d][s] = qkv[b][s][2560+kh*128+d] ----
__global__ __launch_bounds__(256) void v_trans_k(const u16* __restrict__ qkv,
                                                 u16* __restrict__ vT) {
  __shared__ u16 tile[64][65];
  const int s0 = blockIdx.x * 64, d0 = blockIdx.y * 64;
  const int bk = blockIdx.z;  // b*4+kh
  const int b = bk >> 2, kh = bk & 3;
  const int tx = threadIdx.x & 63, ty = threadIdx.x >> 6;
  const u16* src = qkv + ((size_t)b * 2048) * 3072 + 2560 + kh * 128;
#pragma unroll
  for (int jj = 0; jj < 16; ++jj) {
    int s = ty + jj * 4;
    tile[s][tx] = src[(size_t)(s0 + s) * 3072 + d0 + tx];
  }
  __syncthreads();
  u16* dst = vT + (((size_t)bk * 128 + d0) * 2048) + s0;
#pragma unroll
  for (int jj = 0; jj < 16; ++jj) {
    int dd = ty + jj * 4;
    dst[(size_t)dd * 2048 + tx] = tile[tx][dd];
  }
}

// ---------------- GEMM: C[M][N] = A[M][K] * BT[N][K]^T (all bf16, fp32 acc) --
__global__ __launch_bounds__(256) void gemm_bt_k(const u16* __restrict__ A,
                                                 const u16* __restrict__ BT,
                                                 u16* __restrict__ C, int M,
                                                 int N, int Kd) {
  __shared__ __align__(16) u16 lA[128 * 32];
  __shared__ __align__(16) u16 lB[128 * 32];
  const int t = threadIdx.x;
  const int lane = t & 63, lo = lane & 15, hi = lane >> 4;
  const int w = t >> 6, wm = w >> 1, wn = w & 1;
  const int m0 = blockIdx.y * 128, n0 = blockIdx.x * 128;
  const int srow = t >> 2, sslot = t & 3;

  f32x4 acc[4][4];
#pragma unroll
  for (int a = 0; a < 4; ++a)
#pragma unroll
    for (int c = 0; c < 4; ++c) acc[a][c] = (f32x4){0.f, 0.f, 0.f, 0.f};

  const int nk = Kd >> 5;
  for (int kt = 0; kt < nk; ++kt) {
    const int k0 = kt << 5;
    __syncthreads();
#pragma unroll
    for (int i = 0; i < 2; ++i) {
      int r = i * 64 + srow;
      int gs = sslot ^ (r & 3);
      gload16((const char*)A + ((size_t)(m0 + r) * Kd + k0 + gs * 8) * 2,
              (char*)lA + i * 4096 + w * 1024);
    }
#pragma unroll
    for (int i = 0; i < 2; ++i) {
      int r = i * 64 + srow;
      int gs = sslot ^ (r & 3);
      gload16((const char*)BT + ((size_t)(n0 + r) * Kd + k0 + gs * 8) * 2,
              (char*)lB + i * 4096 + w * 1024);
    }
    __syncthreads();

    short8v af[4], bfv[4];
#pragma unroll
    for (int mt = 0; mt < 4; ++mt) {
      int r = wm * 64 + mt * 16 + lo;
      af[mt] = *(const short8v*)((const char*)lA + r * 64 + ((hi ^ (r & 3)) << 4));
    }
#pragma unroll
    for (int nt = 0; nt < 4; ++nt) {
      int r = wn * 64 + nt * 16 + lo;
      bfv[nt] = *(const short8v*)((const char*)lB + r * 64 + ((hi ^ (r & 3)) << 4));
    }
#pragma unroll
    for (int mt = 0; mt < 4; ++mt)
#pragma unroll
      for (int nt = 0; nt < 4; ++nt)
        acc[mt][nt] = __builtin_amdgcn_mfma_f32_16x16x32_bf16(
            af[mt], bfv[nt], acc[mt][nt], 0, 0, 0);
  }

#pragma unroll
  for (int mt = 0; mt < 4; ++mt)
#pragma unroll
    for (int nt = 0; nt < 4; ++nt)
#pragma unroll
      for (int r = 0; r < 4; ++r) {
        int row = m0 + wm * 64 + mt * 16 + hi * 4 + r;
        int col = n0 + wn * 64 + nt * 16 + lo;
        C[(size_t)row * N + col] = f2b(acc[mt][nt][r]);
      }
}

// ---------------- flash attention ----------------
// Q [b][h][s][128], K [b][kh][s][128], VT [b][kh][d][s] -> Y [b][s][h*128+d]
__global__ __launch_bounds__(256) void attn_k(const u16* __restrict__ Q,
                                              const u16* __restrict__ K,
                                              const u16* __restrict__ VT,
                                              u16* __restrict__ Y) {
  __shared__ __align__(16) u16 lK[64 * 128];
  __shared__ __align__(16) u16 lV[128 * 64];
  __shared__ __align__(16) u16 lP[4][16 * 72];

  const int t = threadIdx.x;
  const int lane = t & 63, lo = lane & 15, hi = lane >> 4;
  const int w = t >> 6;

  const int qt = (int)gridDim.x - 1 - (int)blockIdx.x;  // heavy blocks first
  const int bh = blockIdx.y;
  const int b = bh >> 4, h = bh & 15, kh = h >> 2;

  const size_t qbase = ((size_t)(b * 16 + h)) * 2048 * 128;
  const size_t kbase = ((size_t)(b * 4 + kh)) * 2048 * 128;
  const size_t vbase = ((size_t)(b * 4 + kh)) * 128 * 2048;

  const int q0 = qt * 64;
  const int qrow0 = q0 + w * 16 + hi * 4;  // + r

  short8v qf[4];
  {
    const u16* qp = Q + qbase + (size_t)(q0 + w * 16 + lo) * 128;
#pragma unroll
    for (int ks = 0; ks < 4; ++ks)
      qf[ks] = *(const short8v*)(qp + ks * 32 + hi * 8);
  }

  float m_run[4], l_run[4];
#pragma unroll
  for (int r = 0; r < 4; ++r) { m_run[r] = -3.0e38f; l_run[r] = 0.f; }
  f32x4 oacc[8];
#pragma unroll
  for (int ot = 0; ot < 8; ++ot) oacc[ot] = (f32x4){0.f, 0.f, 0.f, 0.f};

  const float scale = 0.08838834764831845f;  // 1/sqrt(128)
  const int ntile = qt + 1;

  for (int j = 0; j < ntile; ++j) {
    const int kv0 = j * 64;
    __syncthreads();
    // stage K tile [64 rows][128 d] (256B rows, 16 slots, xor-swz by row&7)
#pragma unroll
    for (int i = 0; i < 4; ++i) {
      int off = i * 4096 + t * 16;
      int r = off >> 8;
      int sl = (off >> 4) & 15;
      int gs = sl ^ (r & 7);
      gload16((const char*)K + (kbase + (size_t)(kv0 + r) * 128 + gs * 8) * 2,
              (char*)lK + i * 4096 + w * 1024);
    }
    // stage VT tile [128 d-rows][64 s] (128B rows, 8 slots)
#pragma unroll
    for (int i = 0; i < 4; ++i) {
      int off = i * 4096 + t * 16;
      int r = off >> 7;
      int sl = (off >> 4) & 7;
      int gs = sl ^ (r & 7);
      gload16((const char*)VT + (vbase + (size_t)r * 2048 + kv0 + gs * 8) * 2,
              (char*)lV + i * 4096 + w * 1024);
    }
    __syncthreads();

    // QK^T : 16x64 per wave
    f32x4 sacc[4];
#pragma unroll
    for (int nt = 0; nt < 4; ++nt) sacc[nt] = (f32x4){0.f, 0.f, 0.f, 0.f};
#pragma unroll
    for (int ks = 0; ks < 4; ++ks) {
#pragma unroll
      for (int nt = 0; nt < 4; ++nt) {
        int r = nt * 16 + lo;
        int sl = (ks * 4 + hi) ^ (r & 7);
        short8v kf = *(const short8v*)((const char*)lK + r * 256 + (sl << 4));
        sacc[nt] =
            __builtin_amdgcn_mfma_f32_16x16x32_bf16(qf[ks], kf, sacc[nt], 0, 0, 0);
      }
    }

    const bool diag = (j == ntile - 1);
    float pvv[4][4];
    float mx[4];
#pragma unroll
    for (int r = 0; r < 4; ++r) mx[r] = -3.0e38f;
#pragma unroll
    for (int nt = 0; nt < 4; ++nt) {
      int kpos = kv0 + nt * 16 + lo;
#pragma unroll
      for (int r = 0; r < 4; ++r) {
        float v = sacc[nt][r] * scale;
        if (diag && kpos > qrow0 + r) v = -3.0e38f;
        pvv[nt][r] = v;
        mx[r] = fmaxf(mx[r], v);
      }
    }
#pragma unroll
    for (int dm = 1; dm < 16; dm <<= 1) {
#pragma unroll
      for (int r = 0; r < 4; ++r) mx[r] = fmaxf(mx[r], __shfl_xor(mx[r], dm, 64));
    }
    float corr[4], rs[4];
#pragma unroll
    for (int r = 0; r < 4; ++r) {
      float mnew = fmaxf(m_run[r], mx[r]);
      corr[r] = __expf(m_run[r] - mnew);
      m_run[r] = mnew;
      rs[r] = 0.f;
    }
#pragma unroll
    for (int nt = 0; nt < 4; ++nt)
#pragma unroll
      for (int r = 0; r < 4; ++r) {
        float p = __expf(pvv[nt][r] - m_run[r]);
        pvv[nt][r] = p;
        rs[r] += p;
      }
#pragma unroll
    for (int dm = 1; dm < 16; dm <<= 1) {
#pragma unroll
      for (int r = 0; r < 4; ++r) rs[r] += __shfl_xor(rs[r], dm, 64);
    }
#pragma unroll
    for (int r = 0; r < 4; ++r) l_run[r] = l_run[r] * corr[r] + rs[r];
#pragma unroll
    for (int ot = 0; ot < 8; ++ot)
#pragma unroll
      for (int r = 0; r < 4; ++r) oacc[ot][r] *= corr[r];

    // P -> LDS (bf16), per-wave region
    u16* pw = lP[w];
#pragma unroll
    for (int nt = 0; nt < 4; ++nt)
#pragma unroll
      for (int r = 0; r < 4; ++r)
        pw[(hi * 4 + r) * 72 + nt * 16 + lo] = f2b(pvv[nt][r]);

    __syncthreads();

    // PV : O(16x128) += P(16x64) @ V(64x128)
#pragma unroll
    for (int ks = 0; ks < 2; ++ks) {
      short8v pa =
          *(const short8v*)((const char*)pw + lo * 144 + ks * 64 + hi * 16);
#pragma unroll
      for (int ot = 0; ot < 8; ++ot) {
        int r = ot * 16 + lo;
        int sl = (ks * 4 + hi) ^ (r & 7);
        short8v vf = *(const short8v*)((const char*)lV + r * 128 + (sl << 4));
        oacc[ot] =
            __builtin_amdgcn_mfma_f32_16x16x32_bf16(pa, vf, oacc[ot], 0, 0, 0);
      }
    }
  }

#pragma unroll
  for (int ot = 0; ot < 8; ++ot)
#pragma unroll
    for (int r = 0; r < 4; ++r) {
      int srow = qrow0 + r;
      Y[((size_t)b * 2048 + srow) * 2048 + h * 128 + ot * 16 + lo] =
          f2b(oacc[ot][r] / l_run[r]);
    }
}

// ---------------- RMSNorm ----------------
__global__ __launch_bounds__(256) void rmsnorm_k(const u16* __restrict__ Yb,
                                                 const float* __restrict__ nw,
                                                 float* __restrict__ out) {
  const int row = blockIdx.x;
  const int t = threadIdx.x;
  const u16* yr = Yb + (size_t)row * 2048 + t * 8;
  short8v v = *(const short8v*)yr;
  float x[8];
  float ss = 0.f;
#pragma unroll
  for (int j = 0; j < 8; ++j) {
    x[j] = b2f((u16)v[j]);
    ss += x[j] * x[j];
  }
#pragma unroll
  for (int dm = 1; dm < 64; dm <<= 1) ss += __shfl_xor(ss, dm, 64);
  __shared__ float red[4];
  if ((t & 63) == 0) red[t >> 6] = ss;
  __syncthreads();
  float tot = red[0] + red[1] + red[2] + red[3];
  float inv = rsqrtf(tot * (1.0f / 2048.0f) + 1e-6f);
  float* op = out + (size_t)row * 2048 + t * 8;
  const float* wp = nw + t * 8;
  f32x4 o0, o1;
#pragma unroll
  for (int j = 0; j < 4; ++j) o0[j] = x[j] * inv * wp[j];
#pragma unroll
  for (int j = 0; j < 4; ++j) o1[j] = x[4 + j] * inv * wp[4 + j];
  *(f32x4*)op = o0;
  *(f32x4*)(op + 4) = o1;
}

extern "C" void kernel_launch(void* const* d_in, const int* in_sizes, int n_in,
                              void* d_out, int out_size, void* d_ws,
                              size_t ws_size, hipStream_t stream) {
  (void)in_sizes; (void)n_in; (void)out_size; (void)ws_size;
  const float* x = (const float*)d_in[0];
  const float* w_attn = (const float*)d_in[1];
  const float* w_proj = (const float*)d_in[2];
  const float* norm_w = (const float*)d_in[3];
  float* out = (float*)d_out;
  char* ws = (char*)d_ws;

  size_t off = 0;
  auto alloc = [&](size_t n) {
    size_t r = off;
    off += (n + 255) & ~(size_t)255;
    return r;
  };
  u16* xb = (u16*)(ws + alloc(33554432));     // x bf16 [8192][2048]
  u16* wabT = (u16*)(ws + alloc(12582912));   // w_attn^T bf16 [3072][2048]
  u16* qkv = (u16*)(ws + alloc(50331648));    // [8192][3072]
  u16* q_r = (u16*)(ws + alloc(33554432));    // [4][16][2048][128]
  u16* vT = (u16*)(ws + alloc(8388608));      // [4][4][128][2048]
  u16* wpT = (u16*)(ws + alloc(8388608));     // w_proj^T bf16 [2048][2048]
  float* cosT = (float*)(ws + alloc(524288)); // [2048][64]
  float* sinT = (float*)(ws + alloc(524288));
  u16* k_r = wabT;  // reuse (dead after GEMM1): [4][4][2048][128]
  u16* y = xb;      // reuse (dead after GEMM1): attn out [8192][2048]
  u16* y2 = qkv;    // reuse (dead after rope/vtrans): proj out [8192][2048]

  cvt_x_k<<<8192, 256, 0, stream>>>(x, xb);
  transpose_cvt_k<<<dim3(48, 32), 256, 0, stream>>>(w_attn, wabT, 2048, 3072);
  transpose_cvt_k<<<dim3(32, 32), 256, 0, stream>>>(w_proj, wpT, 2048, 2048);
  rope_table_k<<<512, 256, 0, stream>>>(cosT, sinT);
  gemm_bt_k<<<dim3(24, 64), 256, 0, stream>>>(xb, wabT, qkv, 8192, 3072, 2048);
  rope_scatter_k<<<8192, 256, 0, stream>>>(qkv, cosT, sinT, q_r, k_r);
  v_trans_k<<<dim3(32, 2, 16), 256, 0, stream>>>(qkv, vT);
  attn_k<<<dim3(32, 64), 256, 0, stream>>>(q_r, k_r, vT, y);
  gemm_bt_k<<<dim3(16, 64), 256, 0, stream>>>(y, wpT, y2, 8192, 2048, 2048);
  rmsnorm_k<<<8192, 256, 0, stream>>>(y2, norm_w, out);
}

// Round 2
// 609.702 us; speedup vs baseline: 1.0563x; 1.0563x over previous
//
#include <hip/hip_runtime.h>

#define DEVI __device__ __forceinline__

using u16 = unsigned short;
using u32 = unsigned int;

typedef __attribute__((ext_vector_type(8))) short short8v;
typedef __attribute__((ext_vector_type(4))) float f32x4;

DEVI u16 f2b(float f) {
  u32 u = __builtin_bit_cast(u32, f);
  u += 0x7fffu + ((u >> 16) & 1u);
  return (u16)(u >> 16);
}
DEVI float b2f(u16 b) { return __builtin_bit_cast(float, (u32)b << 16); }

DEVI void gload16(const void* g, void* l) {
  __builtin_amdgcn_global_load_lds(
      (const __attribute__((address_space(1))) void*)g,
      (__attribute__((address_space(3))) void*)l, 16, 0, 0);
}

// ---------------- x: fp32 -> bf16 ----------------
__global__ __launch_bounds__(256) void cvt_x_k(const float* __restrict__ in,
                                               u16* __restrict__ out) {
  size_t i = ((size_t)blockIdx.x * 256 + threadIdx.x) * 8;
  f32x4 a = *(const f32x4*)(in + i);
  f32x4 c = *(const f32x4*)(in + i + 4);
  short8v o;
  o[0] = (short)f2b(a[0]); o[1] = (short)f2b(a[1]);
  o[2] = (short)f2b(a[2]); o[3] = (short)f2b(a[3]);
  o[4] = (short)f2b(c[0]); o[5] = (short)f2b(c[1]);
  o[6] = (short)f2b(c[2]); o[7] = (short)f2b(c[3]);
  *(short8v*)(out + i) = o;
}

// ---------------- transpose + cvt: out[c][r] = bf16(in[r][c]) ----------------
__global__ __launch_bounds__(256) void transpose_cvt_k(
    const float* __restrict__ in, u16* __restrict__ out, int R, int Ccols) {
  __shared__ u16 tile[64][65];
  const int r0 = blockIdx.y * 64, c0 = blockIdx.x * 64;
  const int tx = threadIdx.x & 63, ty = threadIdx.x >> 6;
#pragma unroll
  for (int jj = 0; jj < 16; ++jj) {
    int r = ty + jj * 4;
    tile[r][tx] = f2b(in[(size_t)(r0 + r) * Ccols + c0 + tx]);
  }
  __syncthreads();
#pragma unroll
  for (int jj = 0; jj < 16; ++jj) {
    int c = ty + jj * 4;
    out[(size_t)(c0 + c) * R + r0 + tx] = tile[tx][c];
  }
}

// ---------------- rope table: cos/sin[s][i], i in [0,64) ----------------
__global__ __launch_bounds__(256) void rope_table_k(float* __restrict__ cosT,
                                                    float* __restrict__ sinT) {
  int idx = blockIdx.x * 256 + threadIdx.x;
  int s = idx >> 6, i = idx & 63;
  float inv_freq = expf(-(float)i * (1.0f / 64.0f) * 9.210340371976184f);
  float ang = (float)s * inv_freq;
  cosT[idx] = cosf(ang);
  sinT[idx] = sinf(ang);
}

// ---------------- rope + scatter q,k ----------------
__global__ __launch_bounds__(256) void rope_scatter_k(
    const u16* __restrict__ qkv, const float* __restrict__ cosT,
    const float* __restrict__ sinT, u16* __restrict__ q_r,
    u16* __restrict__ k_r) {
  const int row = blockIdx.x;
  const int b = row >> 11, s = row & 2047;
  const u16* in = qkv + (size_t)row * 3072;
  const float* cp = cosT + s * 64;
  const float* sp = sinT + s * 64;
  for (int p = threadIdx.x; p < 1280; p += 256) {
    int f0 = p * 2;
    u32 pair = *(const u32*)(in + f0);
    float x0 = b2f((u16)(pair & 0xffffu));
    float x1 = b2f((u16)(pair >> 16));
    int d, head;
    u16* dst;
    if (f0 < 2048) {
      head = f0 >> 7; d = f0 & 127;
      dst = q_r + (((size_t)(b * 16 + head)) * 2048 + s) * 128 + d;
    } else {
      int idx = f0 - 2048;
      head = idx >> 7; d = idx & 127;
      dst = k_r + (((size_t)(b * 4 + head)) * 2048 + s) * 128 + d;
    }
    int i = d >> 1;
    float c = cp[i], sn = sp[i];
    float o0 = x0 * c - x1 * sn;
    float o1 = x0 * sn + x1 * c;
    *(u32*)dst = (u32)f2b(o0) | ((u32)f2b(o1) << 16);
  }
}

// ---------------- v transpose ----------------
__global__ __launch_bounds__(256) void v_trans_k(const u16* __restrict__ qkv,
                                                 u16* __restrict__ vT) {
  __shared__ u16 tile[64][65];
  const int s0 = blockIdx.x * 64, d0 = blockIdx.y * 64;
  const int bk = blockIdx.z;
  const int b = bk >> 2, kh = bk & 3;
  const int tx = threadIdx.x & 63, ty = threadIdx.x >> 6;
  const u16* src = qkv + ((size_t)b * 2048) * 3072 + 2560 + kh * 128;
#pragma unroll
  for (int jj = 0; jj < 16; ++jj) {
    int s = ty + jj * 4;
    tile[s][tx] = src[(size_t)(s0 + s) * 3072 + d0 + tx];
  }
  __syncthreads();
  u16* dst = vT + (((size_t)bk * 128 + d0) * 2048) + s0;
#pragma unroll
  for (int jj = 0; jj < 16; ++jj) {
    int dd = ty + jj * 4;
    dst[(size_t)dd * 2048 + tx] = tile[tx][dd];
  }
}

// ---------------- GEMM: C[M][N] = A[M][K] * BT[N][K]^T ----------------
__global__ __launch_bounds__(256) void gemm_bt_k(const u16* __restrict__ A,
                                                 const u16* __restrict__ BT,
                                                 u16* __restrict__ C, int M,
                                                 int N, int Kd) {
  __shared__ __align__(16) u16 lA[128 * 32];
  __shared__ __align__(16) u16 lB[128 * 32];
  const int t = threadIdx.x;
  const int lane = t & 63, lo = lane & 15, hi = lane >> 4;
  const int w = t >> 6, wm = w >> 1, wn = w & 1;

  // XCD-aware bijective swizzle (nwg % 8 == 0 for both launches)
  const int ntx = gridDim.x;
  const int nwg = ntx * gridDim.y;
  const int orig = blockIdx.y * ntx + blockIdx.x;
  const int cpx = nwg >> 3;
  const int swz = (orig & 7) * cpx + (orig >> 3);
  const int m0 = (swz / ntx) * 128, n0 = (swz % ntx) * 128;

  const int srow = t >> 2, sslot = t & 3;

  f32x4 acc[4][4];
#pragma unroll
  for (int a = 0; a < 4; ++a)
#pragma unroll
    for (int c = 0; c < 4; ++c) acc[a][c] = (f32x4){0.f, 0.f, 0.f, 0.f};

  const int nk = Kd >> 5;
  for (int kt = 0; kt < nk; ++kt) {
    const int k0 = kt << 5;
    __syncthreads();
#pragma unroll
    for (int i = 0; i < 2; ++i) {
      int r = i * 64 + srow;
      int gs = sslot ^ (r & 3);
      gload16((const char*)A + ((size_t)(m0 + r) * Kd + k0 + gs * 8) * 2,
              (char*)lA + i * 4096 + w * 1024);
    }
#pragma unroll
    for (int i = 0; i < 2; ++i) {
      int r = i * 64 + srow;
      int gs = sslot ^ (r & 3);
      gload16((const char*)BT + ((size_t)(n0 + r) * Kd + k0 + gs * 8) * 2,
              (char*)lB + i * 4096 + w * 1024);
    }
    __syncthreads();

    short8v af[4], bfv[4];
#pragma unroll
    for (int mt = 0; mt < 4; ++mt) {
      int r = wm * 64 + mt * 16 + lo;
      af[mt] = *(const short8v*)((const char*)lA + r * 64 + ((hi ^ (r & 3)) << 4));
    }
#pragma unroll
    for (int nt = 0; nt < 4; ++nt) {
      int r = wn * 64 + nt * 16 + lo;
      bfv[nt] = *(const short8v*)((const char*)lB + r * 64 + ((hi ^ (r & 3)) << 4));
    }
    __builtin_amdgcn_s_setprio(1);
#pragma unroll
    for (int mt = 0; mt < 4; ++mt)
#pragma unroll
      for (int nt = 0; nt < 4; ++nt)
        acc[mt][nt] = __builtin_amdgcn_mfma_f32_16x16x32_bf16(
            af[mt], bfv[nt], acc[mt][nt], 0, 0, 0);
    __builtin_amdgcn_s_setprio(0);
  }

#pragma unroll
  for (int mt = 0; mt < 4; ++mt)
#pragma unroll
    for (int nt = 0; nt < 4; ++nt)
#pragma unroll
      for (int r = 0; r < 4; ++r) {
        int row = m0 + wm * 64 + mt * 16 + hi * 4 + r;
        int col = n0 + wn * 64 + nt * 16 + lo;
        C[(size_t)row * N + col] = f2b(acc[mt][nt][r]);
      }
}

// ---------------- flash attention (double-buffered, prefetch pipeline) ------
__global__ __launch_bounds__(256) void attn_k(const u16* __restrict__ Q,
                                              const u16* __restrict__ K,
                                              const u16* __restrict__ VT,
                                              u16* __restrict__ Y) {
  __shared__ __align__(16) u16 lK[2][64 * 128];
  __shared__ __align__(16) u16 lV[2][128 * 64];
  __shared__ __align__(16) u16 lP[4][16 * 72];

  const int t = threadIdx.x;
  const int lane = t & 63, lo = lane & 15, hi = lane >> 4;
  const int w = t >> 6;

  const int qt = (int)gridDim.x - 1 - (int)blockIdx.x;  // heavy blocks first
  const int bh = blockIdx.y;
  const int b = bh >> 4, h = bh & 15, kh = h >> 2;

  const size_t qbase = ((size_t)(b * 16 + h)) * 2048 * 128;
  const size_t kbase = ((size_t)(b * 4 + kh)) * 2048 * 128;
  const size_t vbase = ((size_t)(b * 4 + kh)) * 128 * 2048;

  const int q0 = qt * 64;
  const int qrow0 = q0 + w * 16 + hi * 4;

  short8v qf[4];
  {
    const u16* qp = Q + qbase + (size_t)(q0 + w * 16 + lo) * 128;
#pragma unroll
    for (int ks = 0; ks < 4; ++ks)
      qf[ks] = *(const short8v*)(qp + ks * 32 + hi * 8);
  }

  float m_run[4], l_run[4];
#pragma unroll
  for (int r = 0; r < 4; ++r) { m_run[r] = -3.0e38f; l_run[r] = 0.f; }
  f32x4 oacc[8];
#pragma unroll
  for (int ot = 0; ot < 8; ++ot) oacc[ot] = (f32x4){0.f, 0.f, 0.f, 0.f};

  const float scale = 0.08838834764831845f;
  const int ntile = qt + 1;

  auto stage = [&](int buf, int j) {
    const int kv0 = j * 64;
#pragma unroll
    for (int i = 0; i < 4; ++i) {
      int off = i * 4096 + t * 16;
      int r = off >> 8;
      int sl = (off >> 4) & 15;
      int gs = sl ^ (r & 7);
      gload16((const char*)K + (kbase + (size_t)(kv0 + r) * 128 + gs * 8) * 2,
              (char*)lK[buf] + i * 4096 + w * 1024);
    }
#pragma unroll
    for (int i = 0; i < 4; ++i) {
      int off = i * 4096 + t * 16;
      int r = off >> 7;
      int sl = (off >> 4) & 7;
      int gs = sl ^ (r & 7);
      gload16((const char*)VT + (vbase + (size_t)r * 2048 + kv0 + gs * 8) * 2,
              (char*)lV[buf] + i * 4096 + w * 1024);
    }
  };

  stage(0, 0);
  __syncthreads();  // implicit vmcnt(0) drain: tile 0 resident

  for (int j = 0; j < ntile; ++j) {
    const int cur = j & 1;
    if (j + 1 < ntile) stage(cur ^ 1, j + 1);  // prefetch overlaps compute

    const u16* lKc = lK[cur];
    const u16* lVc = lV[cur];
    const int kv0 = j * 64;

    // QK^T : 16x64 per wave
    f32x4 sacc[4];
#pragma unroll
    for (int nt = 0; nt < 4; ++nt) sacc[nt] = (f32x4){0.f, 0.f, 0.f, 0.f};
    __builtin_amdgcn_s_setprio(1);
#pragma unroll
    for (int ks = 0; ks < 4; ++ks) {
#pragma unroll
      for (int nt = 0; nt < 4; ++nt) {
        int r = nt * 16 + lo;
        int sl = (ks * 4 + hi) ^ (r & 7);
        short8v kf = *(const short8v*)((const char*)lKc + r * 256 + (sl << 4));
        sacc[nt] =
            __builtin_amdgcn_mfma_f32_16x16x32_bf16(qf[ks], kf, sacc[nt], 0, 0, 0);
      }
    }
    __builtin_amdgcn_s_setprio(0);

    const bool diag = (j == ntile - 1);
    float pvv[4][4];
    float mx[4];
#pragma unroll
    for (int r = 0; r < 4; ++r) mx[r] = -3.0e38f;
#pragma unroll
    for (int nt = 0; nt < 4; ++nt) {
      int kpos = kv0 + nt * 16 + lo;
#pragma unroll
      for (int r = 0; r < 4; ++r) {
        float v = sacc[nt][r] * scale;
        if (diag && kpos > qrow0 + r) v = -3.0e38f;
        pvv[nt][r] = v;
        mx[r] = fmaxf(mx[r], v);
      }
    }
#pragma unroll
    for (int dm = 1; dm < 16; dm <<= 1) {
#pragma unroll
      for (int r = 0; r < 4; ++r) mx[r] = fmaxf(mx[r], __shfl_xor(mx[r], dm, 64));
    }
    float corr[4], rs[4];
#pragma unroll
    for (int r = 0; r < 4; ++r) {
      float mnew = fmaxf(m_run[r], mx[r]);
      corr[r] = __expf(m_run[r] - mnew);
      m_run[r] = mnew;
      rs[r] = 0.f;
    }
#pragma unroll
    for (int nt = 0; nt < 4; ++nt)
#pragma unroll
      for (int r = 0; r < 4; ++r) {
        float p = __expf(pvv[nt][r] - m_run[r]);
        pvv[nt][r] = p;
        rs[r] += p;
      }
#pragma unroll
    for (int dm = 1; dm < 16; dm <<= 1) {
#pragma unroll
      for (int r = 0; r < 4; ++r) rs[r] += __shfl_xor(rs[r], dm, 64);
    }
#pragma unroll
    for (int r = 0; r < 4; ++r) l_run[r] = l_run[r] * corr[r] + rs[r];
#pragma unroll
    for (int ot = 0; ot < 8; ++ot)
#pragma unroll
      for (int r = 0; r < 4; ++r) oacc[ot][r] *= corr[r];

    // P -> LDS (wave-private region; lgkmcnt ordering, no barrier needed)
    u16* pw = lP[w];
#pragma unroll
    for (int nt = 0; nt < 4; ++nt)
#pragma unroll
      for (int r = 0; r < 4; ++r)
        pw[(hi * 4 + r) * 72 + nt * 16 + lo] = f2b(pvv[nt][r]);

    // PV : O(16x128) += P(16x64) @ V(64x128)
    __builtin_amdgcn_s_setprio(1);
#pragma unroll
    for (int ks = 0; ks < 2; ++ks) {
      short8v pa =
          *(const short8v*)((const char*)pw + lo * 144 + ks * 64 + hi * 16);
#pragma unroll
      for (int ot = 0; ot < 8; ++ot) {
        int r = ot * 16 + lo;
        int sl = (ks * 4 + hi) ^ (r & 7);
        short8v vf = *(const short8v*)((const char*)lVc + r * 128 + (sl << 4));
        oacc[ot] =
            __builtin_amdgcn_mfma_f32_16x16x32_bf16(pa, vf, oacc[ot], 0, 0, 0);
      }
    }
    __builtin_amdgcn_s_setprio(0);

    __syncthreads();  // drains prefetch vmcnt + syncs buffer swap
  }

#pragma unroll
  for (int ot = 0; ot < 8; ++ot)
#pragma unroll
    for (int r = 0; r < 4; ++r) {
      int srow = qrow0 + r;
      Y[((size_t)b * 2048 + srow) * 2048 + h * 128 + ot * 16 + lo] =
          f2b(oacc[ot][r] / l_run[r]);
    }
}

// ---------------- RMSNorm ----------------
__global__ __launch_bounds__(256) void rmsnorm_k(const u16* __restrict__ Yb,
                                                 const float* __restrict__ nw,
                                                 float* __restrict__ out) {
  const int row = blockIdx.x;
  const int t = threadIdx.x;
  const u16* yr = Yb + (size_t)row * 2048 + t * 8;
  short8v v = *(const short8v*)yr;
  float x[8];
  float ss = 0.f;
#pragma unroll
  for (int j = 0; j < 8; ++j) {
    x[j] = b2f((u16)v[j]);
    ss += x[j] * x[j];
  }
#pragma unroll
  for (int dm = 1; dm < 64; dm <<= 1) ss += __shfl_xor(ss, dm, 64);
  __shared__ float red[4];
  if ((t & 63) == 0) red[t >> 6] = ss;
  __syncthreads();
  float tot = red[0] + red[1] + red[2] + red[3];
  float inv = rsqrtf(tot * (1.0f / 2048.0f) + 1e-6f);
  float* op = out + (size_t)row * 2048 + t * 8;
  const float* wp = nw + t * 8;
  f32x4 o0, o1;
#pragma unroll
  for (int j = 0; j < 4; ++j) o0[j] = x[j] * inv * wp[j];
#pragma unroll
  for (int j = 0; j < 4; ++j) o1[j] = x[4 + j] * inv * wp[4 + j];
  *(f32x4*)op = o0;
  *(f32x4*)(op + 4) = o1;
}

extern "C" void kernel_launch(void* const* d_in, const int* in_sizes, int n_in,
                              void* d_out, int out_size, void* d_ws,
                              size_t ws_size, hipStream_t stream) {
  (void)in_sizes; (void)n_in; (void)out_size; (void)ws_size;
  const float* x = (const float*)d_in[0];
  const float* w_attn = (const float*)d_in[1];
  const float* w_proj = (const float*)d_in[2];
  const float* norm_w = (const float*)d_in[3];
  float* out = (float*)d_out;
  char* ws = (char*)d_ws;

  size_t off = 0;
  auto alloc = [&](size_t n) {
    size_t r = off;
    off += (n + 255) & ~(size_t)255;
    return r;
  };
  u16* xb = (u16*)(ws + alloc(33554432));     // x bf16 [8192][2048]
  u16* wabT = (u16*)(ws + alloc(12582912));   // w_attn^T bf16 [3072][2048]
  u16* qkv = (u16*)(ws + alloc(50331648));    // [8192][3072]
  u16* q_r = (u16*)(ws + alloc(33554432));    // [4][16][2048][128]
  u16* vT = (u16*)(ws + alloc(8388608));      // [4][4][128][2048]
  u16* wpT = (u16*)(ws + alloc(8388608));     // w_proj^T bf16 [2048][2048]
  float* cosT = (float*)(ws + alloc(524288)); // [2048][64]
  float* sinT = (float*)(ws + alloc(524288));
  u16* k_r = wabT;  // reuse (dead after GEMM1): [4][4][2048][128]
  u16* y = xb;      // reuse (dead after GEMM1): attn out [8192][2048]
  u16* y2 = qkv;    // reuse (dead after rope/vtrans): proj out [8192][2048]

  cvt_x_k<<<8192, 256, 0, stream>>>(x, xb);
  transpose_cvt_k<<<dim3(48, 32), 256, 0, stream>>>(w_attn, wabT, 2048, 3072);
  transpose_cvt_k<<<dim3(32, 32), 256, 0, stream>>>(w_proj, wpT, 2048, 2048);
  rope_table_k<<<512, 256, 0, stream>>>(cosT, sinT);
  gemm_bt_k<<<dim3(24, 64), 256, 0, stream>>>(xb, wabT, qkv, 8192, 3072, 2048);
  rope_scatter_k<<<8192, 256, 0, stream>>>(qkv, cosT, sinT, q_r, k_r);
  v_trans_k<<<dim3(32, 2, 16), 256, 0, stream>>>(qkv, vT);
  attn_k<<<dim3(32, 64), 256, 0, stream>>>(q_r, k_r, vT, y);
  gemm_bt_k<<<dim3(16, 64), 256, 0, stream>>>(y, wpT, y2, 8192, 2048, 2048);
  rmsnorm_k<<<8192, 256, 0, stream>>>(y2, norm_w, out);
}

// Round 3
// 449.323 us; speedup vs baseline: 1.4333x; 1.3569x over previous
//
#include <hip/hip_runtime.h>

#define DEVI __device__ __forceinline__

using u16 = unsigned short;
using u32 = unsigned int;

typedef __attribute__((ext_vector_type(8))) short short8v;
typedef __attribute__((ext_vector_type(4))) float f32x4;
typedef __attribute__((ext_vector_type(2))) u32 u32x2;

DEVI u16 f2b(float f) {
  u32 u = __builtin_bit_cast(u32, f);
  u += 0x7fffu + ((u >> 16) & 1u);
  return (u16)(u >> 16);
}
DEVI float b2f(u16 b) { return __builtin_bit_cast(float, (u32)b << 16); }

DEVI void gload16(const void* g, void* l) {
  __builtin_amdgcn_global_load_lds(
      (const __attribute__((address_space(1))) void*)g,
      (__attribute__((address_space(3))) void*)l, 16, 0, 0);
}

// ---------------- x: fp32 -> bf16 ----------------
__global__ __launch_bounds__(256) void cvt_x_k(const float* __restrict__ in,
                                               u16* __restrict__ out) {
  size_t i = ((size_t)blockIdx.x * 256 + threadIdx.x) * 8;
  f32x4 a = *(const f32x4*)(in + i);
  f32x4 c = *(const f32x4*)(in + i + 4);
  short8v o;
  o[0] = (short)f2b(a[0]); o[1] = (short)f2b(a[1]);
  o[2] = (short)f2b(a[2]); o[3] = (short)f2b(a[3]);
  o[4] = (short)f2b(c[0]); o[5] = (short)f2b(c[1]);
  o[6] = (short)f2b(c[2]); o[7] = (short)f2b(c[3]);
  *(short8v*)(out + i) = o;
}

// ---------------- transpose + cvt ----------------
__global__ __launch_bounds__(256) void transpose_cvt_k(
    const float* __restrict__ in, u16* __restrict__ out, int R, int Ccols) {
  __shared__ u16 tile[64][65];
  const int r0 = blockIdx.y * 64, c0 = blockIdx.x * 64;
  const int tx = threadIdx.x & 63, ty = threadIdx.x >> 6;
#pragma unroll
  for (int jj = 0; jj < 16; ++jj) {
    int r = ty + jj * 4;
    tile[r][tx] = f2b(in[(size_t)(r0 + r) * Ccols + c0 + tx]);
  }
  __syncthreads();
#pragma unroll
  for (int jj = 0; jj < 16; ++jj) {
    int c = ty + jj * 4;
    out[(size_t)(c0 + c) * R + r0 + tx] = tile[tx][c];
  }
}

// ---------------- rope table ----------------
__global__ __launch_bounds__(256) void rope_table_k(float* __restrict__ cosT,
                                                    float* __restrict__ sinT) {
  int idx = blockIdx.x * 256 + threadIdx.x;
  int s = idx >> 6, i = idx & 63;
  float inv_freq = expf(-(float)i * (1.0f / 64.0f) * 9.210340371976184f);
  float ang = (float)s * inv_freq;
  cosT[idx] = cosf(ang);
  sinT[idx] = sinf(ang);
}

// ---------------- rope + scatter q,k (q pre-scaled by 1/sqrt(hd)*log2e) ----
__global__ __launch_bounds__(256) void rope_scatter_k(
    const u16* __restrict__ qkv, const float* __restrict__ cosT,
    const float* __restrict__ sinT, u16* __restrict__ q_r,
    u16* __restrict__ k_r) {
  const float QS = 0.08838834764831845f * 1.4426950408889634f;
  const int row = blockIdx.x;
  const int b = row >> 11, s = row & 2047;
  const u16* in = qkv + (size_t)row * 3072;
  const float* cp = cosT + s * 64;
  const float* sp = sinT + s * 64;
  for (int p = threadIdx.x; p < 1280; p += 256) {
    int f0 = p * 2;
    u32 pair = *(const u32*)(in + f0);
    float x0 = b2f((u16)(pair & 0xffffu));
    float x1 = b2f((u16)(pair >> 16));
    int d, head;
    u16* dst;
    bool isq = (f0 < 2048);
    if (isq) {
      head = f0 >> 7; d = f0 & 127;
      dst = q_r + (((size_t)(b * 16 + head)) * 2048 + s) * 128 + d;
    } else {
      int idx = f0 - 2048;
      head = idx >> 7; d = idx & 127;
      dst = k_r + (((size_t)(b * 4 + head)) * 2048 + s) * 128 + d;
    }
    int i = d >> 1;
    float c = cp[i], sn = sp[i];
    float o0 = x0 * c - x1 * sn;
    float o1 = x0 * sn + x1 * c;
    if (isq) { o0 *= QS; o1 *= QS; }
    *(u32*)dst = (u32)f2b(o0) | ((u32)f2b(o1) << 16);
  }
}

// ---------------- v transpose ----------------
__global__ __launch_bounds__(256) void v_trans_k(const u16* __restrict__ qkv,
                                                 u16* __restrict__ vT) {
  __shared__ u16 tile[64][65];
  const int s0 = blockIdx.x * 64, d0 = blockIdx.y * 64;
  const int bk = blockIdx.z;
  const int b = bk >> 2, kh = bk & 3;
  const int tx = threadIdx.x & 63, ty = threadIdx.x >> 6;
  const u16* src = qkv + ((size_t)b * 2048) * 3072 + 2560 + kh * 128;
#pragma unroll
  for (int jj = 0; jj < 16; ++jj) {
    int s = ty + jj * 4;
    tile[s][tx] = src[(size_t)(s0 + s) * 3072 + d0 + tx];
  }
  __syncthreads();
  u16* dst = vT + (((size_t)bk * 128 + d0) * 2048) + s0;
#pragma unroll
  for (int jj = 0; jj < 16; ++jj) {
    int dd = ty + jj * 4;
    dst[(size_t)dd * 2048 + tx] = tile[tx][dd];
  }
}

// ---------------- GEMM: C[M][N] = A[M][K] * BT[N][K]^T ----------------
__global__ __launch_bounds__(256) void gemm_bt_k(const u16* __restrict__ A,
                                                 const u16* __restrict__ BT,
                                                 u16* __restrict__ C, int M,
                                                 int N, int Kd) {
  __shared__ __align__(16) u16 lA[128 * 32];
  __shared__ __align__(16) u16 lB[128 * 32];
  const int t = threadIdx.x;
  const int lane = t & 63, lo = lane & 15, hi = lane >> 4;
  const int w = t >> 6, wm = w >> 1, wn = w & 1;

  const int ntx = gridDim.x;
  const int nwg = ntx * gridDim.y;
  const int orig = blockIdx.y * ntx + blockIdx.x;
  const int cpx = nwg >> 3;
  const int swz = (orig & 7) * cpx + (orig >> 3);
  const int m0 = (swz / ntx) * 128, n0 = (swz % ntx) * 128;

  const int srow = t >> 2, sslot = t & 3;

  f32x4 acc[4][4];
#pragma unroll
  for (int a = 0; a < 4; ++a)
#pragma unroll
    for (int c = 0; c < 4; ++c) acc[a][c] = (f32x4){0.f, 0.f, 0.f, 0.f};

  const int nk = Kd >> 5;
  for (int kt = 0; kt < nk; ++kt) {
    const int k0 = kt << 5;
    __syncthreads();
#pragma unroll
    for (int i = 0; i < 2; ++i) {
      int r = i * 64 + srow;
      int gs = sslot ^ (r & 3);
      gload16((const char*)A + ((size_t)(m0 + r) * Kd + k0 + gs * 8) * 2,
              (char*)lA + i * 4096 + w * 1024);
    }
#pragma unroll
    for (int i = 0; i < 2; ++i) {
      int r = i * 64 + srow;
      int gs = sslot ^ (r & 3);
      gload16((const char*)BT + ((size_t)(n0 + r) * Kd + k0 + gs * 8) * 2,
              (char*)lB + i * 4096 + w * 1024);
    }
    __syncthreads();

    short8v af[4], bfv[4];
#pragma unroll
    for (int mt = 0; mt < 4; ++mt) {
      int r = wm * 64 + mt * 16 + lo;
      af[mt] = *(const short8v*)((const char*)lA + r * 64 + ((hi ^ (r & 3)) << 4));
    }
#pragma unroll
    for (int nt = 0; nt < 4; ++nt) {
      int r = wn * 64 + nt * 16 + lo;
      bfv[nt] = *(const short8v*)((const char*)lB + r * 64 + ((hi ^ (r & 3)) << 4));
    }
    __builtin_amdgcn_s_setprio(1);
#pragma unroll
    for (int mt = 0; mt < 4; ++mt)
#pragma unroll
      for (int nt = 0; nt < 4; ++nt)
        acc[mt][nt] = __builtin_amdgcn_mfma_f32_16x16x32_bf16(
            af[mt], bfv[nt], acc[mt][nt], 0, 0, 0);
    __builtin_amdgcn_s_setprio(0);
  }

#pragma unroll
  for (int mt = 0; mt < 4; ++mt)
#pragma unroll
    for (int nt = 0; nt < 4; ++nt)
#pragma unroll
      for (int r = 0; r < 4; ++r) {
        int row = m0 + wm * 64 + mt * 16 + hi * 4 + r;
        int col = n0 + wn * 64 + nt * 16 + lo;
        C[(size_t)row * N + col] = f2b(acc[mt][nt][r]);
      }
}

// ---------------- flash attention (swapped QK^T, in-register softmax) -------
// Q [b][h][s][128] (pre-scaled), K [b][kh][s][128], VT [b][kh][d][s]
// block: 128 q-rows, 4 waves x 32 rows; KV tile 64.
__global__ __launch_bounds__(256, 2) void attn_k(const u16* __restrict__ Q,
                                                 const u16* __restrict__ K,
                                                 const u16* __restrict__ VT,
                                                 u16* __restrict__ Y) {
  __shared__ __align__(16) u16 lK[2][64 * 128];
  __shared__ __align__(16) u16 lV[2][128 * 64];
  __shared__ __align__(16) u16 lP[4][32 * 64];

  const int t = threadIdx.x;
  const int lane = t & 63, lo = lane & 15, hi = lane >> 4;
  const int w = t >> 6;
  const int L = lo & 7;

  // XCD-concentrating swizzle: each XCD gets 8 bh's; heavy q-tiles first.
  const int id = blockIdx.x;
  const int xcd = id & 7, pos = id >> 3;
  const int bh = xcd + ((pos >> 4) << 3);
  const int qt = 15 - (pos & 15);
  const int b = bh >> 4, h = bh & 15, kh = h >> 2;

  const size_t qbase = (size_t)(b * 16 + h) * 2048 * 128;
  const size_t kbase = (size_t)(b * 4 + kh) * 2048 * 128;
  const size_t vbase = (size_t)(b * 4 + kh) * 128 * 2048;

  const int q0 = qt * 128;
  const int wq0 = q0 + w * 32;

  short8v qf[2][4];
#pragma unroll
  for (int j2 = 0; j2 < 2; ++j2)
#pragma unroll
    for (int ks = 0; ks < 4; ++ks)
      qf[j2][ks] = *(const short8v*)(Q + qbase +
                                     (size_t)(wq0 + j2 * 16 + lo) * 128 +
                                     ks * 32 + hi * 8);

  float m_run[2], l_run[2];
  m_run[0] = -3.0e38f; m_run[1] = -3.0e38f;
  l_run[0] = 0.f; l_run[1] = 0.f;
  f32x4 oacc[2][8];
#pragma unroll
  for (int j2 = 0; j2 < 2; ++j2)
#pragma unroll
    for (int ot = 0; ot < 8; ++ot) oacc[j2][ot] = (f32x4){0.f, 0.f, 0.f, 0.f};

  const int ntile = 2 * qt + 2;

  auto stage = [&](int buf, int j) {
    const int kv0 = j * 64;
#pragma unroll
    for (int i = 0; i < 4; ++i) {
      int off = i * 4096 + t * 16;
      int r = off >> 8;
      int sl = (off >> 4) & 15;
      int gs = sl ^ (r & 7);
      gload16((const char*)K + (kbase + (size_t)(kv0 + r) * 128 + gs * 8) * 2,
              (char*)lK[buf] + i * 4096 + w * 1024);
    }
#pragma unroll
    for (int i = 0; i < 4; ++i) {
      int off = i * 4096 + t * 16;
      int r = off >> 7;
      int sl = (off >> 4) & 7;
      int gs = sl ^ (r & 7);
      gload16((const char*)VT + (vbase + (size_t)r * 2048 + kv0 + gs * 8) * 2,
              (char*)lV[buf] + i * 4096 + w * 1024);
    }
  };

  stage(0, 0);
  __syncthreads();

  u16* pw = lP[w];

  for (int jj = 0; jj < ntile; ++jj) {
    const int cur = jj & 1;
    if (jj + 1 < ntile) stage(cur ^ 1, jj + 1);

    const u16* lKc = lK[cur];
    const u16* lVc = lV[cur];
    const int kv0 = jj * 64;

    // QK^T swapped: S^T frag: q on lo, k on (hi,reg). sacc[j2][kt]
    f32x4 sacc[2][4];
#pragma unroll
    for (int j2 = 0; j2 < 2; ++j2)
#pragma unroll
      for (int kt = 0; kt < 4; ++kt) sacc[j2][kt] = (f32x4){0.f, 0.f, 0.f, 0.f};
    __builtin_amdgcn_s_setprio(1);
#pragma unroll
    for (int ks = 0; ks < 4; ++ks) {
#pragma unroll
      for (int kt = 0; kt < 4; ++kt) {
        int kr = kt * 16 + lo;
        int sl = (ks * 4 + hi) ^ (kr & 7);
        short8v kf = *(const short8v*)((const char*)lKc + kr * 256 + (sl << 4));
        sacc[0][kt] = __builtin_amdgcn_mfma_f32_16x16x32_bf16(kf, qf[0][ks],
                                                              sacc[0][kt], 0, 0, 0);
        sacc[1][kt] = __builtin_amdgcn_mfma_f32_16x16x32_bf16(kf, qf[1][ks],
                                                              sacc[1][kt], 0, 0, 0);
      }
    }
    __builtin_amdgcn_s_setprio(0);

    // causal mask (last two tiles only): k = kv0 + kt*16 + hi*4 + r, q = wq0 + j2*16 + lo
    if (jj >= ntile - 2) {
      const int kb = kv0 + hi * 4 - wq0 - lo;
#pragma unroll
      for (int j2 = 0; j2 < 2; ++j2)
#pragma unroll
        for (int kt = 0; kt < 4; ++kt)
#pragma unroll
          for (int r = 0; r < 4; ++r)
            if (kb + kt * 16 + r - j2 * 16 > 0) sacc[j2][kt][r] = -1.0e38f;
    }

    // row max: in-register tree + 2 shfl
    float pmax[2];
#pragma unroll
    for (int j2 = 0; j2 < 2; ++j2) {
      f32x4 m4;
#pragma unroll
      for (int r = 0; r < 4; ++r)
        m4[r] = fmaxf(fmaxf(sacc[j2][0][r], sacc[j2][1][r]),
                      fmaxf(sacc[j2][2][r], sacc[j2][3][r]));
      float m = fmaxf(fmaxf(m4[0], m4[1]), fmaxf(m4[2], m4[3]));
      m = fmaxf(m, __shfl_xor(m, 16, 64));
      m = fmaxf(m, __shfl_xor(m, 32, 64));
      pmax[j2] = m;
    }

    // defer-max: rescale only when the running max grows materially
    bool need = (pmax[0] > m_run[0] + 8.f) || (pmax[1] > m_run[1] + 8.f);
    if (__any(need)) {
      float corr[2];
#pragma unroll
      for (int j2 = 0; j2 < 2; ++j2) {
        float mn = fmaxf(m_run[j2], pmax[j2]);
        corr[j2] = exp2f(m_run[j2] - mn);
        m_run[j2] = mn;
        l_run[j2] *= corr[j2];
      }
#pragma unroll
      for (int j2 = 0; j2 < 2; ++j2) {
        float c0 = __shfl(corr[j2], hi * 4 + 0, 64);
        float c1 = __shfl(corr[j2], hi * 4 + 1, 64);
        float c2 = __shfl(corr[j2], hi * 4 + 2, 64);
        float c3 = __shfl(corr[j2], hi * 4 + 3, 64);
#pragma unroll
        for (int ot = 0; ot < 8; ++ot) {
          oacc[j2][ot][0] *= c0;
          oacc[j2][ot][1] *= c1;
          oacc[j2][ot][2] *= c2;
          oacc[j2][ot][3] *= c3;
        }
      }
    }

    // p = exp2(s - m); sum; pack to LDS (swizzled b64 writes)
#pragma unroll
    for (int j2 = 0; j2 < 2; ++j2) {
      const float rowm = m_run[j2];
      float s0 = 0.f, s1 = 0.f, s2 = 0.f, s3 = 0.f;
#pragma unroll
      for (int kt = 0; kt < 4; ++kt) {
        float p0 = exp2f(sacc[j2][kt][0] - rowm);
        float p1 = exp2f(sacc[j2][kt][1] - rowm);
        float p2 = exp2f(sacc[j2][kt][2] - rowm);
        float p3 = exp2f(sacc[j2][kt][3] - rowm);
        s0 += p0; s1 += p1; s2 += p2; s3 += p3;
        u32 w0, w1;
        asm("v_cvt_pk_bf16_f32 %0, %1, %2" : "=v"(w0) : "v"(p0), "v"(p1));
        asm("v_cvt_pk_bf16_f32 %0, %1, %2" : "=v"(w1) : "v"(p2), "v"(p3));
        int idx = (j2 * 16 + lo) * 64 + ((kt * 16 + hi * 4) ^ (L << 3));
        *(u32x2*)(pw + idx) = (u32x2){w0, w1};
      }
      float sm = (s0 + s1) + (s2 + s3);
      sm += __shfl_xor(sm, 16, 64);
      sm += __shfl_xor(sm, 32, 64);
      l_run[j2] += sm;
    }

    // PV: O(32x128) += P(32x64) @ V(64x128)
    __builtin_amdgcn_s_setprio(1);
#pragma unroll
    for (int ks = 0; ks < 2; ++ks) {
      short8v pa0 = *(const short8v*)((const char*)pw + (0 * 16 + lo) * 128 +
                                      ((ks * 64 + hi * 16) ^ (L << 4)));
      short8v pa1 = *(const short8v*)((const char*)pw + (16 + lo) * 128 +
                                      ((ks * 64 + hi * 16) ^ (L << 4)));
#pragma unroll
      for (int ot = 0; ot < 8; ++ot) {
        int vr = ot * 16 + lo;
        int sl = (ks * 4 + hi) ^ (vr & 7);
        short8v vf = *(const short8v*)((const char*)lVc + vr * 128 + (sl << 4));
        oacc[0][ot] =
            __builtin_amdgcn_mfma_f32_16x16x32_bf16(pa0, vf, oacc[0][ot], 0, 0, 0);
        oacc[1][ot] =
            __builtin_amdgcn_mfma_f32_16x16x32_bf16(pa1, vf, oacc[1][ot], 0, 0, 0);
      }
    }
    __builtin_amdgcn_s_setprio(0);

    __syncthreads();
  }

  // epilogue: redistribute l to (hi,reg) rows, normalize, store
  float inv[2][4];
#pragma unroll
  for (int j2 = 0; j2 < 2; ++j2)
#pragma unroll
    for (int r = 0; r < 4; ++r) {
      float lv = __shfl(l_run[j2], hi * 4 + r, 64);
      inv[j2][r] = 1.0f / lv;
    }
#pragma unroll
  for (int j2 = 0; j2 < 2; ++j2)
#pragma unroll
    for (int ot = 0; ot < 8; ++ot)
#pragma unroll
      for (int r = 0; r < 4; ++r) {
        int qrow = wq0 + j2 * 16 + hi * 4 + r;
        Y[((size_t)b * 2048 + qrow) * 2048 + h * 128 + ot * 16 + lo] =
            f2b(oacc[j2][ot][r] * inv[j2][r]);
      }
}

// ---------------- RMSNorm ----------------
__global__ __launch_bounds__(256) void rmsnorm_k(const u16* __restrict__ Yb,
                                                 const float* __restrict__ nw,
                                                 float* __restrict__ out) {
  const int row = blockIdx.x;
  const int t = threadIdx.x;
  const u16* yr = Yb + (size_t)row * 2048 + t * 8;
  short8v v = *(const short8v*)yr;
  float x[8];
  float ss = 0.f;
#pragma unroll
  for (int j = 0; j < 8; ++j) {
    x[j] = b2f((u16)v[j]);
    ss += x[j] * x[j];
  }
#pragma unroll
  for (int dm = 1; dm < 64; dm <<= 1) ss += __shfl_xor(ss, dm, 64);
  __shared__ float red[4];
  if ((t & 63) == 0) red[t >> 6] = ss;
  __syncthreads();
  float tot = red[0] + red[1] + red[2] + red[3];
  float inv = rsqrtf(tot * (1.0f / 2048.0f) + 1e-6f);
  float* op = out + (size_t)row * 2048 + t * 8;
  const float* wp = nw + t * 8;
  f32x4 o0, o1;
#pragma unroll
  for (int j = 0; j < 4; ++j) o0[j] = x[j] * inv * wp[j];
#pragma unroll
  for (int j = 0; j < 4; ++j) o1[j] = x[4 + j] * inv * wp[4 + j];
  *(f32x4*)op = o0;
  *(f32x4*)(op + 4) = o1;
}

extern "C" void kernel_launch(void* const* d_in, const int* in_sizes, int n_in,
                              void* d_out, int out_size, void* d_ws,
                              size_t ws_size, hipStream_t stream) {
  (void)in_sizes; (void)n_in; (void)out_size; (void)ws_size;
  const float* x = (const float*)d_in[0];
  const float* w_attn = (const float*)d_in[1];
  const float* w_proj = (const float*)d_in[2];
  const float* norm_w = (const float*)d_in[3];
  float* out = (float*)d_out;
  char* ws = (char*)d_ws;

  size_t off = 0;
  auto alloc = [&](size_t n) {
    size_t r = off;
    off += (n + 255) & ~(size_t)255;
    return r;
  };
  u16* xb = (u16*)(ws + alloc(33554432));     // x bf16 [8192][2048]
  u16* wabT = (u16*)(ws + alloc(12582912));   // w_attn^T bf16 [3072][2048]
  u16* qkv = (u16*)(ws + alloc(50331648));    // [8192][3072]
  u16* q_r = (u16*)(ws + alloc(33554432));    // [4][16][2048][128]
  u16* vT = (u16*)(ws + alloc(8388608));      // [4][4][128][2048]
  u16* wpT = (u16*)(ws + alloc(8388608));     // w_proj^T bf16 [2048][2048]
  float* cosT = (float*)(ws + alloc(524288)); // [2048][64]
  float* sinT = (float*)(ws + alloc(524288));
  u16* k_r = wabT;  // reuse (dead after GEMM1)
  u16* y = xb;      // reuse: attn out [8192][2048]
  u16* y2 = qkv;    // reuse: proj out [8192][2048]

  cvt_x_k<<<8192, 256, 0, stream>>>(x, xb);
  transpose_cvt_k<<<dim3(48, 32), 256, 0, stream>>>(w_attn, wabT, 2048, 3072);
  transpose_cvt_k<<<dim3(32, 32), 256, 0, stream>>>(w_proj, wpT, 2048, 2048);
  rope_table_k<<<512, 256, 0, stream>>>(cosT, sinT);
  gemm_bt_k<<<dim3(24, 64), 256, 0, stream>>>(xb, wabT, qkv, 8192, 3072, 2048);
  rope_scatter_k<<<8192, 256, 0, stream>>>(qkv, cosT, sinT, q_r, k_r);
  v_trans_k<<<dim3(32, 2, 16), 256, 0, stream>>>(qkv, vT);
  attn_k<<<dim3(1024), 256, 0, stream>>>(q_r, k_r, vT, y);
  gemm_bt_k<<<dim3(16, 64), 256, 0, stream>>>(y, wpT, y2, 8192, 2048, 2048);
  rmsnorm_k<<<8192, 256, 0, stream>>>(y2, norm_w, out);
}

// Round 4
// 428.144 us; speedup vs baseline: 1.5042x; 1.0495x over previous
//
#include <hip/hip_runtime.h>

#define DEVI __device__ __forceinline__

using u16 = unsigned short;
using u32 = unsigned int;

typedef __attribute__((ext_vector_type(8))) short short8v;
typedef __attribute__((ext_vector_type(4))) float f32x4;
typedef __attribute__((ext_vector_type(2))) u32 u32x2;

DEVI u16 f2b(float f) {
  u32 u = __builtin_bit_cast(u32, f);
  u += 0x7fffu + ((u >> 16) & 1u);
  return (u16)(u >> 16);
}
DEVI float b2f(u16 b) { return __builtin_bit_cast(float, (u32)b << 16); }

DEVI void gload16(const void* g, void* l) {
  __builtin_amdgcn_global_load_lds(
      (const __attribute__((address_space(1))) void*)g,
      (__attribute__((address_space(3))) void*)l, 16, 0, 0);
}

// ---------------- x: fp32 -> bf16 ----------------
__global__ __launch_bounds__(256) void cvt_x_k(const float* __restrict__ in,
                                               u16* __restrict__ out) {
  size_t i = ((size_t)blockIdx.x * 256 + threadIdx.x) * 8;
  f32x4 a = *(const f32x4*)(in + i);
  f32x4 c = *(const f32x4*)(in + i + 4);
  short8v o;
  o[0] = (short)f2b(a[0]); o[1] = (short)f2b(a[1]);
  o[2] = (short)f2b(a[2]); o[3] = (short)f2b(a[3]);
  o[4] = (short)f2b(c[0]); o[5] = (short)f2b(c[1]);
  o[6] = (short)f2b(c[2]); o[7] = (short)f2b(c[3]);
  *(short8v*)(out + i) = o;
}

// ---------------- transpose + cvt ----------------
__global__ __launch_bounds__(256) void transpose_cvt_k(
    const float* __restrict__ in, u16* __restrict__ out, int R, int Ccols) {
  __shared__ u16 tile[64][65];
  const int r0 = blockIdx.y * 64, c0 = blockIdx.x * 64;
  const int tx = threadIdx.x & 63, ty = threadIdx.x >> 6;
#pragma unroll
  for (int jj = 0; jj < 16; ++jj) {
    int r = ty + jj * 4;
    tile[r][tx] = f2b(in[(size_t)(r0 + r) * Ccols + c0 + tx]);
  }
  __syncthreads();
#pragma unroll
  for (int jj = 0; jj < 16; ++jj) {
    int c = ty + jj * 4;
    out[(size_t)(c0 + c) * R + r0 + tx] = tile[tx][c];
  }
}

// ---------------- rope table ----------------
__global__ __launch_bounds__(256) void rope_table_k(float* __restrict__ cosT,
                                                    float* __restrict__ sinT) {
  int idx = blockIdx.x * 256 + threadIdx.x;
  int s = idx >> 6, i = idx & 63;
  float inv_freq = expf(-(float)i * (1.0f / 64.0f) * 9.210340371976184f);
  float ang = (float)s * inv_freq;
  cosT[idx] = cosf(ang);
  sinT[idx] = sinf(ang);
}

// ---------------- rope + scatter q,k (q pre-scaled by 1/sqrt(hd)*log2e) ----
__global__ __launch_bounds__(256) void rope_scatter_k(
    const u16* __restrict__ qkv, const float* __restrict__ cosT,
    const float* __restrict__ sinT, u16* __restrict__ q_r,
    u16* __restrict__ k_r) {
  const float QS = 0.08838834764831845f * 1.4426950408889634f;
  const int row = blockIdx.x;
  const int b = row >> 11, s = row & 2047;
  const u16* in = qkv + (size_t)row * 3072;
  const float* cp = cosT + s * 64;
  const float* sp = sinT + s * 64;
  for (int p = threadIdx.x; p < 1280; p += 256) {
    int f0 = p * 2;
    u32 pair = *(const u32*)(in + f0);
    float x0 = b2f((u16)(pair & 0xffffu));
    float x1 = b2f((u16)(pair >> 16));
    int d, head;
    u16* dst;
    bool isq = (f0 < 2048);
    if (isq) {
      head = f0 >> 7; d = f0 & 127;
      dst = q_r + (((size_t)(b * 16 + head)) * 2048 + s) * 128 + d;
    } else {
      int idx = f0 - 2048;
      head = idx >> 7; d = idx & 127;
      dst = k_r + (((size_t)(b * 4 + head)) * 2048 + s) * 128 + d;
    }
    int i = d >> 1;
    float c = cp[i], sn = sp[i];
    float o0 = x0 * c - x1 * sn;
    float o1 = x0 * sn + x1 * c;
    if (isq) { o0 *= QS; o1 *= QS; }
    *(u32*)dst = (u32)f2b(o0) | ((u32)f2b(o1) << 16);
  }
}

// ---------------- v transpose ----------------
__global__ __launch_bounds__(256) void v_trans_k(const u16* __restrict__ qkv,
                                                 u16* __restrict__ vT) {
  __shared__ u16 tile[64][65];
  const int s0 = blockIdx.x * 64, d0 = blockIdx.y * 64;
  const int bk = blockIdx.z;
  const int b = bk >> 2, kh = bk & 3;
  const int tx = threadIdx.x & 63, ty = threadIdx.x >> 6;
  const u16* src = qkv + ((size_t)b * 2048) * 3072 + 2560 + kh * 128;
#pragma unroll
  for (int jj = 0; jj < 16; ++jj) {
    int s = ty + jj * 4;
    tile[s][tx] = src[(size_t)(s0 + s) * 3072 + d0 + tx];
  }
  __syncthreads();
  u16* dst = vT + (((size_t)bk * 128 + d0) * 2048) + s0;
#pragma unroll
  for (int jj = 0; jj < 16; ++jj) {
    int dd = ty + jj * 4;
    dst[(size_t)dd * 2048 + tx] = tile[tx][dd];
  }
}

// ---------------- 256x256 8-phase GEMM: C[M][N] = A[M][K] * BT[N][K]^T ------
// 512 threads, 8 waves (2M x 4N), per-wave 128x64. BK=64, K-split half-tiles
// (256 rows x 32 k = 16KB, 2 gload16/thread). LDS 128KB double-buffered.
// vmcnt(4) only at phases 4 and 8. Raw s_barrier (no vmcnt drain).
DEVI short8v ldf(const char* half, int r, int slot) {
  return *(const short8v*)(half + r * 64 + (((slot) ^ (r & 3)) << 4));
}

DEVI void stg(const u16* __restrict__ G, int row0, int Kd, int T, int kh,
              char* dst, int t, int w) {
#pragma unroll
  for (int i = 0; i < 2; ++i) {
    int off = i * 8192 + t * 16;
    int r = off >> 6;
    int gs = ((off >> 4) & 3) ^ (r & 3);
    gload16((const char*)G +
                (((size_t)(row0 + r) * Kd) + T * 64 + kh * 32 + gs * 8) * 2,
            dst + i * 8192 + w * 1024);
  }
}

#define VM4 asm volatile("s_waitcnt vmcnt(4)" ::: "memory")
#define PH(P2, KS, CH, STAGE_STMT, TAILWAIT)                                   \
  {                                                                            \
    if ((CH) == 0) {                                                           \
      _Pragma("unroll") for (int mt = 0; mt < 8; ++mt) af[mt] =                \
          ldf(Ab + (P2) * 32768 + (KS) * 16384, wm * 128 + mt * 16 + lo, hi);  \
    }                                                                          \
    bf0 = ldf(Bb + (P2) * 32768 + (KS) * 16384, wn * 64 + (CH) * 32 + lo, hi);\
    bf1 = ldf(Bb + (P2) * 32768 + (KS) * 16384,                                \
              wn * 64 + (CH) * 32 + 16 + lo, hi);                              \
    STAGE_STMT;                                                                \
    __builtin_amdgcn_sched_barrier(0);                                         \
    __builtin_amdgcn_s_barrier();                                              \
    asm volatile("s_waitcnt lgkmcnt(0)" ::: "memory");                         \
    __builtin_amdgcn_sched_barrier(0);                                         \
    __builtin_amdgcn_s_setprio(1);                                             \
    _Pragma("unroll") for (int mt = 0; mt < 8; ++mt) {                         \
      acc[mt][(CH) * 2] = __builtin_amdgcn_mfma_f32_16x16x32_bf16(             \
          af[mt], bf0, acc[mt][(CH) * 2], 0, 0, 0);                            \
      acc[mt][(CH) * 2 + 1] = __builtin_amdgcn_mfma_f32_16x16x32_bf16(         \
          af[mt], bf1, acc[mt][(CH) * 2 + 1], 0, 0, 0);                        \
    }                                                                          \
    __builtin_amdgcn_s_setprio(0);                                             \
    TAILWAIT;                                                                  \
    __builtin_amdgcn_sched_barrier(0);                                         \
    __builtin_amdgcn_s_barrier();                                              \
    __builtin_amdgcn_sched_barrier(0);                                         \
  }

__global__ __launch_bounds__(512, 2) void gemm256_k(const u16* __restrict__ A,
                                                    const u16* __restrict__ BT,
                                                    u16* __restrict__ C, int N,
                                                    int Kd) {
  __shared__ __align__(16) char lds[131072];
  char* Ab = lds;
  char* Bb = lds + 65536;

  const int t = threadIdx.x;
  const int lane = t & 63, lo = lane & 15, hi = lane >> 4;
  const int w = t >> 6, wm = w >> 2, wn = w & 3;

  const int ntx = gridDim.x;
  const int nwg = ntx * gridDim.y;
  const int orig = blockIdx.y * ntx + blockIdx.x;
  const int cpx = nwg >> 3;
  const int swz = (orig & 7) * cpx + (orig >> 3);
  const int m0 = (swz / ntx) * 256, n0 = (swz % ntx) * 256;

  f32x4 acc[8][4];
#pragma unroll
  for (int a = 0; a < 8; ++a)
#pragma unroll
    for (int c = 0; c < 4; ++c) acc[a][c] = (f32x4){0.f, 0.f, 0.f, 0.f};

  short8v af[8], bf0, bf1;

  const int NK = Kd >> 6;   // 64-wide K-tiles
  const int NK2 = NK >> 1;  // pairs

  // prologue: T0 all 4 halves, T1 kh0 halves
  stg(A, m0, Kd, 0, 0, Ab + 0, t, w);
  stg(BT, n0, Kd, 0, 0, Bb + 0, t, w);
  stg(A, m0, Kd, 0, 1, Ab + 16384, t, w);
  stg(BT, n0, Kd, 0, 1, Bb + 16384, t, w);
  stg(A, m0, Kd, 1, 0, Ab + 32768, t, w);
  stg(BT, n0, Kd, 1, 0, Bb + 32768, t, w);
  VM4;  // T0 landed; T1-kh0 pair in flight
  __builtin_amdgcn_sched_barrier(0);
  __builtin_amdgcn_s_barrier();
  __builtin_amdgcn_sched_barrier(0);

  for (int kt2 = 0; kt2 < NK2; ++kt2) {
    int T1v = 2 * kt2 + 1;
    int T2v = 2 * kt2 + 2; if (T2v > NK - 1) T2v = NK - 1;
    int T3v = 2 * kt2 + 3; if (T3v > NK - 1) T3v = NK - 1;
    PH(0, 0, 0, stg(A, m0, Kd, T1v, 1, Ab + 49152, t, w), (void)0);
    PH(0, 0, 1, stg(BT, n0, Kd, T1v, 1, Bb + 49152, t, w), (void)0);
    PH(0, 1, 0, stg(A, m0, Kd, T2v, 0, Ab + 0, t, w), (void)0);
    PH(0, 1, 1, stg(BT, n0, Kd, T2v, 0, Bb + 0, t, w), VM4);
    PH(1, 0, 0, stg(A, m0, Kd, T2v, 1, Ab + 16384, t, w), (void)0);
    PH(1, 0, 1, stg(BT, n0, Kd, T2v, 1, Bb + 16384, t, w), (void)0);
    PH(1, 1, 0, stg(A, m0, Kd, T3v, 0, Ab + 32768, t, w), (void)0);
    PH(1, 1, 1, stg(BT, n0, Kd, T3v, 0, Bb + 32768, t, w), VM4);
  }
  asm volatile("s_waitcnt vmcnt(0)" ::: "memory");  // drain before endpgm

#pragma unroll
  for (int mt = 0; mt < 8; ++mt)
#pragma unroll
    for (int nt = 0; nt < 4; ++nt)
#pragma unroll
      for (int r = 0; r < 4; ++r) {
        int row = m0 + wm * 128 + mt * 16 + hi * 4 + r;
        int col = n0 + wn * 64 + nt * 16 + lo;
        C[(size_t)row * N + col] = f2b(acc[mt][nt][r]);
      }
}

// ---------------- flash attention (swapped QK^T, in-register softmax) -------
// KVBLK=32, LDS 40KB -> 3 blocks/CU.
__global__ __launch_bounds__(256, 3) void attn_k(const u16* __restrict__ Q,
                                                 const u16* __restrict__ K,
                                                 const u16* __restrict__ VT,
                                                 u16* __restrict__ Y) {
  __shared__ __align__(16) u16 lK[2][32 * 128];
  __shared__ __align__(16) u16 lV[2][128 * 32];
  __shared__ __align__(16) u16 lP[4][32 * 32];

  const int t = threadIdx.x;
  const int lane = t & 63, lo = lane & 15, hi = lane >> 4;
  const int w = t >> 6;

  const int id = blockIdx.x;
  const int xcd = id & 7, pos = id >> 3;
  const int bh = xcd + ((pos >> 4) << 3);
  const int qt = 15 - (pos & 15);
  const int b = bh >> 4, h = bh & 15, kh = h >> 2;

  const size_t qbase = (size_t)(b * 16 + h) * 2048 * 128;
  const size_t kbase = (size_t)(b * 4 + kh) * 2048 * 128;
  const size_t vbase = (size_t)(b * 4 + kh) * 128 * 2048;

  const int q0 = qt * 128;
  const int wq0 = q0 + w * 32;

  short8v qf[2][4];
#pragma unroll
  for (int j2 = 0; j2 < 2; ++j2)
#pragma unroll
    for (int ks = 0; ks < 4; ++ks)
      qf[j2][ks] = *(const short8v*)(Q + qbase +
                                     (size_t)(wq0 + j2 * 16 + lo) * 128 +
                                     ks * 32 + hi * 8);

  float m_run[2], l_run[2];
  m_run[0] = -3.0e38f; m_run[1] = -3.0e38f;
  l_run[0] = 0.f; l_run[1] = 0.f;
  f32x4 oacc[2][8];
#pragma unroll
  for (int j2 = 0; j2 < 2; ++j2)
#pragma unroll
    for (int ot = 0; ot < 8; ++ot) oacc[j2][ot] = (f32x4){0.f, 0.f, 0.f, 0.f};

  const int ntile = 4 * qt + 4;

  auto stage = [&](int buf, int j) {
    const int kv0 = j * 32;
#pragma unroll
    for (int i = 0; i < 2; ++i) {
      int off = i * 4096 + t * 16;
      int r = off >> 8;
      int sl = (off >> 4) & 15;
      int gs = sl ^ (r & 7);
      gload16((const char*)K + (kbase + (size_t)(kv0 + r) * 128 + gs * 8) * 2,
              (char*)lK[buf] + i * 4096 + w * 1024);
    }
#pragma unroll
    for (int i = 0; i < 2; ++i) {
      int off = i * 4096 + t * 16;
      int r = off >> 6;
      int sl = (off >> 4) & 3;
      int gs = sl ^ (r & 3);
      gload16((const char*)VT + (vbase + (size_t)r * 2048 + kv0 + gs * 8) * 2,
              (char*)lV[buf] + i * 4096 + w * 1024);
    }
  };

  stage(0, 0);
  __syncthreads();

  u16* pw = lP[w];

  for (int jj = 0; jj < ntile; ++jj) {
    const int cur = jj & 1;
    if (jj + 1 < ntile) stage(cur ^ 1, jj + 1);

    const u16* lKc = lK[cur];
    const u16* lVc = lV[cur];
    const int kv0 = jj * 32;

    // QK^T swapped: q on lo, k on (hi,reg). sacc[j2][kt]
    f32x4 sacc[2][2];
#pragma unroll
    for (int j2 = 0; j2 < 2; ++j2)
#pragma unroll
      for (int kt = 0; kt < 2; ++kt) sacc[j2][kt] = (f32x4){0.f, 0.f, 0.f, 0.f};
    __builtin_amdgcn_s_setprio(1);
#pragma unroll
    for (int ks = 0; ks < 4; ++ks) {
#pragma unroll
      for (int kt = 0; kt < 2; ++kt) {
        int kr = kt * 16 + lo;
        int sl = (ks * 4 + hi) ^ (kr & 7);
        short8v kf = *(const short8v*)((const char*)lKc + kr * 256 + (sl << 4));
        sacc[0][kt] = __builtin_amdgcn_mfma_f32_16x16x32_bf16(kf, qf[0][ks],
                                                              sacc[0][kt], 0, 0, 0);
        sacc[1][kt] = __builtin_amdgcn_mfma_f32_16x16x32_bf16(kf, qf[1][ks],
                                                              sacc[1][kt], 0, 0, 0);
      }
    }
    __builtin_amdgcn_s_setprio(0);

    // causal mask (tiles overlapping the 128-row diagonal block)
    if (jj >= ntile - 4) {
      const int kb = kv0 + hi * 4 - wq0 - lo;
#pragma unroll
      for (int j2 = 0; j2 < 2; ++j2)
#pragma unroll
        for (int kt = 0; kt < 2; ++kt)
#pragma unroll
          for (int r = 0; r < 4; ++r)
            if (kb + kt * 16 + r - j2 * 16 > 0) sacc[j2][kt][r] = -1.0e38f;
    }

    // row max: in-register tree + 2 shfl
    float pmax[2];
#pragma unroll
    for (int j2 = 0; j2 < 2; ++j2) {
      f32x4 m4;
#pragma unroll
      for (int r = 0; r < 4; ++r) m4[r] = fmaxf(sacc[j2][0][r], sacc[j2][1][r]);
      float m = fmaxf(fmaxf(m4[0], m4[1]), fmaxf(m4[2], m4[3]));
      m = fmaxf(m, __shfl_xor(m, 16, 64));
      m = fmaxf(m, __shfl_xor(m, 32, 64));
      pmax[j2] = m;
    }

    bool need = (pmax[0] > m_run[0] + 8.f) || (pmax[1] > m_run[1] + 8.f);
    if (__any(need)) {
      float corr[2];
#pragma unroll
      for (int j2 = 0; j2 < 2; ++j2) {
        float mn = fmaxf(m_run[j2], pmax[j2]);
        corr[j2] = exp2f(m_run[j2] - mn);
        m_run[j2] = mn;
        l_run[j2] *= corr[j2];
      }
#pragma unroll
      for (int j2 = 0; j2 < 2; ++j2) {
        float c0 = __shfl(corr[j2], hi * 4 + 0, 64);
        float c1 = __shfl(corr[j2], hi * 4 + 1, 64);
        float c2 = __shfl(corr[j2], hi * 4 + 2, 64);
        float c3 = __shfl(corr[j2], hi * 4 + 3, 64);
#pragma unroll
        for (int ot = 0; ot < 8; ++ot) {
          oacc[j2][ot][0] *= c0;
          oacc[j2][ot][1] *= c1;
          oacc[j2][ot][2] *= c2;
          oacc[j2][ot][3] *= c3;
        }
      }
    }

    // p = exp2(s - m); sum; pack to LDS (16B-slot swizzle by lo&3)
#pragma unroll
    for (int j2 = 0; j2 < 2; ++j2) {
      const float rowm = m_run[j2];
      float s0 = 0.f, s1 = 0.f, s2 = 0.f, s3 = 0.f;
#pragma unroll
      for (int kt = 0; kt < 2; ++kt) {
        float p0 = exp2f(sacc[j2][kt][0] - rowm);
        float p1 = exp2f(sacc[j2][kt][1] - rowm);
        float p2 = exp2f(sacc[j2][kt][2] - rowm);
        float p3 = exp2f(sacc[j2][kt][3] - rowm);
        s0 += p0; s1 += p1; s2 += p2; s3 += p3;
        u32 w0, w1;
        asm("v_cvt_pk_bf16_f32 %0, %1, %2" : "=v"(w0) : "v"(p0), "v"(p1));
        asm("v_cvt_pk_bf16_f32 %0, %1, %2" : "=v"(w1) : "v"(p2), "v"(p3));
        int byte = ((((kt * 2 + (hi >> 1)) ^ (lo & 3)) << 4) | ((hi & 1) << 3));
        *(u32x2*)((char*)pw + (j2 * 16 + lo) * 64 + byte) = (u32x2){w0, w1};
      }
      float sm = (s0 + s1) + (s2 + s3);
      sm += __shfl_xor(sm, 16, 64);
      sm += __shfl_xor(sm, 32, 64);
      l_run[j2] += sm;
    }

    // PV: O(32x128) += P(32x32) @ V(32x128)
    __builtin_amdgcn_s_setprio(1);
    {
      short8v pa0 = *(const short8v*)((const char*)pw + lo * 64 +
                                      ((hi ^ (lo & 3)) << 4));
      short8v pa1 = *(const short8v*)((const char*)pw + (16 + lo) * 64 +
                                      ((hi ^ (lo & 3)) << 4));
#pragma unroll
      for (int ot = 0; ot < 8; ++ot) {
        int vr = ot * 16 + lo;
        int sl = hi ^ (vr & 3);
        short8v vf = *(const short8v*)((const char*)lVc + vr * 64 + (sl << 4));
        oacc[0][ot] =
            __builtin_amdgcn_mfma_f32_16x16x32_bf16(pa0, vf, oacc[0][ot], 0, 0, 0);
        oacc[1][ot] =
            __builtin_amdgcn_mfma_f32_16x16x32_bf16(pa1, vf, oacc[1][ot], 0, 0, 0);
      }
    }
    __builtin_amdgcn_s_setprio(0);

    __syncthreads();
  }

  float inv[2][4];
#pragma unroll
  for (int j2 = 0; j2 < 2; ++j2)
#pragma unroll
    for (int r = 0; r < 4; ++r) {
      float lv = __shfl(l_run[j2], hi * 4 + r, 64);
      inv[j2][r] = 1.0f / lv;
    }
#pragma unroll
  for (int j2 = 0; j2 < 2; ++j2)
#pragma unroll
    for (int ot = 0; ot < 8; ++ot)
#pragma unroll
      for (int r = 0; r < 4; ++r) {
        int qrow = wq0 + j2 * 16 + hi * 4 + r;
        Y[((size_t)b * 2048 + qrow) * 2048 + h * 128 + ot * 16 + lo] =
            f2b(oacc[j2][ot][r] * inv[j2][r]);
      }
}

// ---------------- RMSNorm ----------------
__global__ __launch_bounds__(256) void rmsnorm_k(const u16* __restrict__ Yb,
                                                 const float* __restrict__ nw,
                                                 float* __restrict__ out) {
  const int row = blockIdx.x;
  const int t = threadIdx.x;
  const u16* yr = Yb + (size_t)row * 2048 + t * 8;
  short8v v = *(const short8v*)yr;
  float x[8];
  float ss = 0.f;
#pragma unroll
  for (int j = 0; j < 8; ++j) {
    x[j] = b2f((u16)v[j]);
    ss += x[j] * x[j];
  }
#pragma unroll
  for (int dm = 1; dm < 64; dm <<= 1) ss += __shfl_xor(ss, dm, 64);
  __shared__ float red[4];
  if ((t & 63) == 0) red[t >> 6] = ss;
  __syncthreads();
  float tot = red[0] + red[1] + red[2] + red[3];
  float inv = rsqrtf(tot * (1.0f / 2048.0f) + 1e-6f);
  float* op = out + (size_t)row * 2048 + t * 8;
  const float* wp = nw + t * 8;
  f32x4 o0, o1;
#pragma unroll
  for (int j = 0; j < 4; ++j) o0[j] = x[j] * inv * wp[j];
#pragma unroll
  for (int j = 0; j < 4; ++j) o1[j] = x[4 + j] * inv * wp[4 + j];
  *(f32x4*)op = o0;
  *(f32x4*)(op + 4) = o1;
}

extern "C" void kernel_launch(void* const* d_in, const int* in_sizes, int n_in,
                              void* d_out, int out_size, void* d_ws,
                              size_t ws_size, hipStream_t stream) {
  (void)in_sizes; (void)n_in; (void)out_size; (void)ws_size;
  const float* x = (const float*)d_in[0];
  const float* w_attn = (const float*)d_in[1];
  const float* w_proj = (const float*)d_in[2];
  const float* norm_w = (const float*)d_in[3];
  float* out = (float*)d_out;
  char* ws = (char*)d_ws;

  size_t off = 0;
  auto alloc = [&](size_t n) {
    size_t r = off;
    off += (n + 255) & ~(size_t)255;
    return r;
  };
  u16* xb = (u16*)(ws + alloc(33554432));     // x bf16 [8192][2048]
  u16* wabT = (u16*)(ws + alloc(12582912));   // w_attn^T bf16 [3072][2048]
  u16* qkv = (u16*)(ws + alloc(50331648));    // [8192][3072]
  u16* q_r = (u16*)(ws + alloc(33554432));    // [4][16][2048][128]
  u16* vT = (u16*)(ws + alloc(8388608));      // [4][4][128][2048]
  u16* wpT = (u16*)(ws + alloc(8388608));     // w_proj^T bf16 [2048][2048]
  float* cosT = (float*)(ws + alloc(524288)); // [2048][64]
  float* sinT = (float*)(ws + alloc(524288));
  u16* k_r = wabT;  // reuse (dead after GEMM1)
  u16* y = xb;      // reuse: attn out [8192][2048]
  u16* y2 = qkv;    // reuse: proj out [8192][2048]

  cvt_x_k<<<8192, 256, 0, stream>>>(x, xb);
  transpose_cvt_k<<<dim3(48, 32), 256, 0, stream>>>(w_attn, wabT, 2048, 3072);
  transpose_cvt_k<<<dim3(32, 32), 256, 0, stream>>>(w_proj, wpT, 2048, 2048);
  rope_table_k<<<512, 256, 0, stream>>>(cosT, sinT);
  gemm256_k<<<dim3(12, 32), 512, 0, stream>>>(xb, wabT, qkv, 3072, 2048);
  rope_scatter_k<<<8192, 256, 0, stream>>>(qkv, cosT, sinT, q_r, k_r);
  v_trans_k<<<dim3(32, 2, 16), 256, 0, stream>>>(qkv, vT);
  attn_k<<<dim3(1024), 256, 0, stream>>>(q_r, k_r, vT, y);
  gemm256_k<<<dim3(8, 32), 512, 0, stream>>>(y, wpT, y2, 2048, 2048);
  rmsnorm_k<<<8192, 256, 0, stream>>>(y2, norm_w, out);
}

// Round 7
// 404.543 us; speedup vs baseline: 1.5919x; 1.0583x over previous
//
#include <hip/hip_runtime.h>

#define DEVI __device__ __forceinline__

using u16 = unsigned short;
using u32 = unsigned int;

typedef __attribute__((ext_vector_type(8))) short short8v;
typedef __attribute__((ext_vector_type(4))) float f32x4;
typedef __attribute__((ext_vector_type(16))) float f32x16;
typedef __attribute__((ext_vector_type(2))) u32 u32x2;
typedef __attribute__((ext_vector_type(4))) u32 u32x4;

DEVI u16 f2b(float f) {
  u32 u = __builtin_bit_cast(u32, f);
  u += 0x7fffu + ((u >> 16) & 1u);
  return (u16)(u >> 16);
}
DEVI float b2f(u16 b) { return __builtin_bit_cast(float, (u32)b << 16); }

DEVI void gload16(const void* g, void* l) {
  __builtin_amdgcn_global_load_lds(
      (const __attribute__((address_space(1))) void*)g,
      (__attribute__((address_space(3))) void*)l, 16, 0, 0);
}

// ---------------- x: fp32 -> bf16 ----------------
__global__ __launch_bounds__(256) void cvt_x_k(const float* __restrict__ in,
                                               u16* __restrict__ out) {
  size_t i = ((size_t)blockIdx.x * 256 + threadIdx.x) * 8;
  f32x4 a = *(const f32x4*)(in + i);
  f32x4 c = *(const f32x4*)(in + i + 4);
  short8v o;
  o[0] = (short)f2b(a[0]); o[1] = (short)f2b(a[1]);
  o[2] = (short)f2b(a[2]); o[3] = (short)f2b(a[3]);
  o[4] = (short)f2b(c[0]); o[5] = (short)f2b(c[1]);
  o[6] = (short)f2b(c[2]); o[7] = (short)f2b(c[3]);
  *(short8v*)(out + i) = o;
}

// ---------------- transpose + cvt ----------------
__global__ __launch_bounds__(256) void transpose_cvt_k(
    const float* __restrict__ in, u16* __restrict__ out, int R, int Ccols) {
  __shared__ u16 tile[64][65];
  const int r0 = blockIdx.y * 64, c0 = blockIdx.x * 64;
  const int tx = threadIdx.x & 63, ty = threadIdx.x >> 6;
#pragma unroll
  for (int jj = 0; jj < 16; ++jj) {
    int r = ty + jj * 4;
    tile[r][tx] = f2b(in[(size_t)(r0 + r) * Ccols + c0 + tx]);
  }
  __syncthreads();
#pragma unroll
  for (int jj = 0; jj < 16; ++jj) {
    int c = ty + jj * 4;
    out[(size_t)(c0 + c) * R + r0 + tx] = tile[tx][c];
  }
}

// ---------------- rope table ----------------
__global__ __launch_bounds__(256) void rope_table_k(float* __restrict__ cosT,
                                                    float* __restrict__ sinT) {
  int idx = blockIdx.x * 256 + threadIdx.x;
  int s = idx >> 6, i = idx & 63;
  float inv_freq = expf(-(float)i * (1.0f / 64.0f) * 9.210340371976184f);
  float ang = (float)s * inv_freq;
  cosT[idx] = cosf(ang);
  sinT[idx] = sinf(ang);
}

// ---------------- rope + scatter q,k (q pre-scaled by 1/sqrt(hd)*log2e) ----
__global__ __launch_bounds__(256) void rope_scatter_k(
    const u16* __restrict__ qkv, const float* __restrict__ cosT,
    const float* __restrict__ sinT, u16* __restrict__ q_r,
    u16* __restrict__ k_r) {
  const float QS = 0.08838834764831845f * 1.4426950408889634f;
  const int row = blockIdx.x;
  const int b = row >> 11, s = row & 2047;
  const u16* in = qkv + (size_t)row * 3072;
  const float* cp = cosT + s * 64;
  const float* sp = sinT + s * 64;
  for (int p = threadIdx.x; p < 1280; p += 256) {
    int f0 = p * 2;
    u32 pair = *(const u32*)(in + f0);
    float x0 = b2f((u16)(pair & 0xffffu));
    float x1 = b2f((u16)(pair >> 16));
    int d, head;
    u16* dst;
    bool isq = (f0 < 2048);
    if (isq) {
      head = f0 >> 7; d = f0 & 127;
      dst = q_r + (((size_t)(b * 16 + head)) * 2048 + s) * 128 + d;
    } else {
      int idx = f0 - 2048;
      head = idx >> 7; d = idx & 127;
      dst = k_r + (((size_t)(b * 4 + head)) * 2048 + s) * 128 + d;
    }
    int i = d >> 1;
    float c = cp[i], sn = sp[i];
    float o0 = x0 * c - x1 * sn;
    float o1 = x0 * sn + x1 * c;
    if (isq) { o0 *= QS; o1 *= QS; }
    *(u32*)dst = (u32)f2b(o0) | ((u32)f2b(o1) << 16);
  }
}

// ---------------- v transpose ----------------
__global__ __launch_bounds__(256) void v_trans_k(const u16* __restrict__ qkv,
                                                 u16* __restrict__ vT) {
  __shared__ u16 tile[64][65];
  const int s0 = blockIdx.x * 64, d0 = blockIdx.y * 64;
  const int bk = blockIdx.z;
  const int b = bk >> 2, kh = bk & 3;
  const int tx = threadIdx.x & 63, ty = threadIdx.x >> 6;
  const u16* src = qkv + ((size_t)b * 2048) * 3072 + 2560 + kh * 128;
#pragma unroll
  for (int jj = 0; jj < 16; ++jj) {
    int s = ty + jj * 4;
    tile[s][tx] = src[(size_t)(s0 + s) * 3072 + d0 + tx];
  }
  __syncthreads();
  u16* dst = vT + (((size_t)bk * 128 + d0) * 2048) + s0;
#pragma unroll
  for (int jj = 0; jj < 16; ++jj) {
    int dd = ty + jj * 4;
    dst[(size_t)dd * 2048 + tx] = tile[tx][dd];
  }
}

// ---------------- 256x256 8-phase GEMM ----------------
DEVI short8v ldf(const char* half, int r, int slot) {
  return *(const short8v*)(half + r * 64 + (((slot) ^ (r & 3)) << 4));
}

DEVI void stg(const u16* __restrict__ G, int row0, int Kd, int T, int kh,
              char* dst, int t, int w) {
#pragma unroll
  for (int i = 0; i < 2; ++i) {
    int off = i * 8192 + t * 16;
    int r = off >> 6;
    int gs = ((off >> 4) & 3) ^ (r & 3);
    gload16((const char*)G +
                (((size_t)(row0 + r) * Kd) + T * 64 + kh * 32 + gs * 8) * 2,
            dst + i * 8192 + w * 1024);
  }
}

#define VM4 asm volatile("s_waitcnt vmcnt(4)" ::: "memory")
#define PH(P2, KS, CH, STAGE_STMT, TAILWAIT)                                   \
  {                                                                            \
    if ((CH) == 0) {                                                           \
      _Pragma("unroll") for (int mt = 0; mt < 8; ++mt) af[mt] =                \
          ldf(Ab + (P2) * 32768 + (KS) * 16384, wm * 128 + mt * 16 + lo, hi);  \
    }                                                                          \
    bf0 = ldf(Bb + (P2) * 32768 + (KS) * 16384, wn * 64 + (CH) * 32 + lo, hi);\
    bf1 = ldf(Bb + (P2) * 32768 + (KS) * 16384,                                \
              wn * 64 + (CH) * 32 + 16 + lo, hi);                              \
    STAGE_STMT;                                                                \
    __builtin_amdgcn_sched_barrier(0);                                         \
    __builtin_amdgcn_s_barrier();                                              \
    asm volatile("s_waitcnt lgkmcnt(0)" ::: "memory");                         \
    __builtin_amdgcn_sched_barrier(0);                                         \
    __builtin_amdgcn_s_setprio(1);                                             \
    _Pragma("unroll") for (int mt = 0; mt < 8; ++mt) {                         \
      acc[mt][(CH) * 2] = __builtin_amdgcn_mfma_f32_16x16x32_bf16(             \
          af[mt], bf0, acc[mt][(CH) * 2], 0, 0, 0);                            \
      acc[mt][(CH) * 2 + 1] = __builtin_amdgcn_mfma_f32_16x16x32_bf16(         \
          af[mt], bf1, acc[mt][(CH) * 2 + 1], 0, 0, 0);                        \
    }                                                                          \
    __builtin_amdgcn_s_setprio(0);                                             \
    TAILWAIT;                                                                  \
    __builtin_amdgcn_sched_barrier(0);                                         \
    __builtin_amdgcn_s_barrier();                                              \
    __builtin_amdgcn_sched_barrier(0);                                         \
  }

__global__ __launch_bounds__(512, 2) void gemm256_k(const u16* __restrict__ A,
                                                    const u16* __restrict__ BT,
                                                    u16* __restrict__ C, int N,
                                                    int Kd) {
  __shared__ __align__(16) char lds[131072];
  char* Ab = lds;
  char* Bb = lds + 65536;

  const int t = threadIdx.x;
  const int lane = t & 63, lo = lane & 15, hi = lane >> 4;
  const int w = t >> 6, wm = w >> 2, wn = w & 3;

  const int ntx = gridDim.x;
  const int nwg = ntx * gridDim.y;
  const int orig = blockIdx.y * ntx + blockIdx.x;
  const int cpx = nwg >> 3;
  const int swz = (orig & 7) * cpx + (orig >> 3);
  const int m0 = (swz / ntx) * 256, n0 = (swz % ntx) * 256;

  f32x4 acc[8][4];
#pragma unroll
  for (int a = 0; a < 8; ++a)
#pragma unroll
    for (int c = 0; c < 4; ++c) acc[a][c] = (f32x4){0.f, 0.f, 0.f, 0.f};

  short8v af[8], bf0, bf1;

  const int NK = Kd >> 6;
  const int NK2 = NK >> 1;

  stg(A, m0, Kd, 0, 0, Ab + 0, t, w);
  stg(BT, n0, Kd, 0, 0, Bb + 0, t, w);
  stg(A, m0, Kd, 0, 1, Ab + 16384, t, w);
  stg(BT, n0, Kd, 0, 1, Bb + 16384, t, w);
  stg(A, m0, Kd, 1, 0, Ab + 32768, t, w);
  stg(BT, n0, Kd, 1, 0, Bb + 32768, t, w);
  VM4;
  __builtin_amdgcn_sched_barrier(0);
  __builtin_amdgcn_s_barrier();
  __builtin_amdgcn_sched_barrier(0);

  for (int kt2 = 0; kt2 < NK2; ++kt2) {
    int T1v = 2 * kt2 + 1;
    int T2v = 2 * kt2 + 2; if (T2v > NK - 1) T2v = NK - 1;
    int T3v = 2 * kt2 + 3; if (T3v > NK - 1) T3v = NK - 1;
    PH(0, 0, 0, stg(A, m0, Kd, T1v, 1, Ab + 49152, t, w), (void)0);
    PH(0, 0, 1, stg(BT, n0, Kd, T1v, 1, Bb + 49152, t, w), (void)0);
    PH(0, 1, 0, stg(A, m0, Kd, T2v, 0, Ab + 0, t, w), (void)0);
    PH(0, 1, 1, stg(BT, n0, Kd, T2v, 0, Bb + 0, t, w), VM4);
    PH(1, 0, 0, stg(A, m0, Kd, T2v, 1, Ab + 16384, t, w), (void)0);
    PH(1, 0, 1, stg(BT, n0, Kd, T2v, 1, Bb + 16384, t, w), (void)0);
    PH(1, 1, 0, stg(A, m0, Kd, T3v, 0, Ab + 32768, t, w), (void)0);
    PH(1, 1, 1, stg(BT, n0, Kd, T3v, 0, Bb + 32768, t, w), VM4);
  }
  asm volatile("s_waitcnt vmcnt(0)" ::: "memory");

#pragma unroll
  for (int mt = 0; mt < 8; ++mt)
#pragma unroll
    for (int nt = 0; nt < 4; ++nt)
#pragma unroll
      for (int r = 0; r < 4; ++r) {
        int row = m0 + wm * 128 + mt * 16 + hi * 4 + r;
        int col = n0 + wn * 64 + nt * 16 + lo;
        C[(size_t)row * N + col] = f2b(acc[mt][nt][r]);
      }
}

// ---------------- flash attention: 32x32 MFMA, in-register P ----------------
// Swapped operands: S^T = mfma(K, Q) -> q on lane&31 (lane-local softmax);
// O^T = mfma(V^T, P^T) -> q on lane&31 again. P^T built in-register via
// cvt_pk_bf16 + permlane32_swap (no P LDS). LDS 64KB -> 2 blocks/CU.
__global__ __launch_bounds__(256, 2) void attn_k(const u16* __restrict__ Q,
                                                 const u16* __restrict__ K,
                                                 const u16* __restrict__ VT,
                                                 u16* __restrict__ Y) {
  __shared__ __align__(16) u16 lK[2][64 * 128];
  __shared__ __align__(16) u16 lV[2][128 * 64];

  const int t = threadIdx.x;
  const int lane = t & 63;
  const int l31 = lane & 31, hb = lane >> 5;
  const int w = t >> 6;

  const int id = blockIdx.x;
  const int xcd = id & 7, pos = id >> 3;
  const int bh = xcd + ((pos >> 4) << 3);
  const int qt = 15 - (pos & 15);  // heavy q-tiles first
  const int b = bh >> 4, h = bh & 15, kh = h >> 2;

  const size_t qbase = (size_t)(b * 16 + h) * 2048 * 128;
  const size_t kbase = (size_t)(b * 4 + kh) * 2048 * 128;
  const size_t vbase = (size_t)(b * 4 + kh) * 128 * 2048;

  const int q0 = qt * 128;
  const int qrow = q0 + w * 32 + l31;

  // Q fragments: B-operand, q = lane&31, d = j16*16 + hb*8 + e
  short8v qf[8];
#pragma unroll
  for (int j16 = 0; j16 < 8; ++j16)
    qf[j16] = *(const short8v*)(Q + qbase + (size_t)qrow * 128 + j16 * 16 + hb * 8);

  float m_run = -3.0e38f, l_run = 0.f;
  f32x16 oacc[4];
#pragma unroll
  for (int db = 0; db < 4; ++db)
#pragma unroll
    for (int rg = 0; rg < 16; ++rg) oacc[db][rg] = 0.f;

  const int ntile = 2 * qt + 2;

  auto stage = [&](int buf, int j) {
    const int kv0 = j * 64;
#pragma unroll
    for (int i = 0; i < 4; ++i) {
      int off = i * 4096 + t * 16;
      int r = off >> 8;
      int sl = (off >> 4) & 15;
      int gs = sl ^ (r & 7);
      gload16((const char*)K + (kbase + (size_t)(kv0 + r) * 128 + gs * 8) * 2,
              (char*)lK[buf] + i * 4096 + w * 1024);
    }
#pragma unroll
    for (int i = 0; i < 4; ++i) {
      int off = i * 4096 + t * 16;
      int r = off >> 7;
      int sl = (off >> 4) & 7;
      int gs = sl ^ (r & 7);
      gload16((const char*)VT + (vbase + (size_t)r * 2048 + kv0 + gs * 8) * 2,
              (char*)lV[buf] + i * 4096 + w * 1024);
    }
  };

  stage(0, 0);
  __syncthreads();

  for (int jj = 0; jj < ntile; ++jj) {
    const int cur = jj & 1;
    if (jj + 1 < ntile) stage(cur ^ 1, jj + 1);

    const char* lKc = (const char*)lK[cur];
    const char* lVc = (const char*)lV[cur];
    const int kv0 = jj * 64;

    // QK^T: S^T[k][q], k = kv0 + kb*32 + (rg&3)+8*(rg>>2)+4*hb, q = qrow
    f32x16 sacc[2];
#pragma unroll
    for (int kb = 0; kb < 2; ++kb)
#pragma unroll
      for (int rg = 0; rg < 16; ++rg) sacc[kb][rg] = 0.f;

    __builtin_amdgcn_s_setprio(1);
#pragma unroll
    for (int j16 = 0; j16 < 8; ++j16) {
      const int c = j16 * 2 + hb;
#pragma unroll
      for (int kb = 0; kb < 2; ++kb) {
        int kr = kb * 32 + l31;
        // read XOR matches the stage-write involution (r&7)
        short8v kf = *(const short8v*)(lKc + kr * 256 + ((c ^ (kr & 7)) << 4));
        sacc[kb] = __builtin_amdgcn_mfma_f32_32x32x16_bf16(kf, qf[j16],
                                                           sacc[kb], 0, 0, 0);
      }
    }
    __builtin_amdgcn_s_setprio(0);

    // causal mask (last two tiles cover the diagonal 128-block)
    if (jj >= ntile - 2) {
      const int mb = kv0 + 4 * hb - qrow;
#pragma unroll
      for (int kb = 0; kb < 2; ++kb)
#pragma unroll
        for (int rg = 0; rg < 16; ++rg)
          if (mb + kb * 32 + (rg & 3) + 8 * (rg >> 2) > 0)
            sacc[kb][rg] = -1.0e38f;
    }

    // lane-local row max (+1 cross-half shfl)
    float mx = sacc[0][0];
#pragma unroll
    for (int rg = 1; rg < 16; ++rg) mx = fmaxf(mx, sacc[0][rg]);
#pragma unroll
    for (int rg = 0; rg < 16; ++rg) mx = fmaxf(mx, sacc[1][rg]);
    mx = fmaxf(mx, __shfl_xor(mx, 32, 64));

    // defer-max rescale (lane-local corr; no redistribution)
    if (__any(mx > m_run + 8.f)) {
      float mn = fmaxf(m_run, mx);
      float corr = exp2f(m_run - mn);
      m_run = mn;
      l_run *= corr;
#pragma unroll
      for (int db = 0; db < 4; ++db)
#pragma unroll
        for (int rg = 0; rg < 16; ++rg) oacc[db][rg] *= corr;
    }

    // p = exp2(s - m); row sum; pack P^T fragments in-register
    float sm = 0.f;
#pragma unroll
    for (int kb = 0; kb < 2; ++kb)
#pragma unroll
      for (int rg = 0; rg < 16; ++rg) {
        float p = exp2f(sacc[kb][rg] - m_run);
        sacc[kb][rg] = p;
        sm += p;
      }
    sm += __shfl_xor(sm, 32, 64);
    l_run += sm;

    // Word contents per lane-half hb (s rel. to kv0+kb*32):
    //  pw00: hb0 {0,1}  hb1 {4,5}    pw10: hb0 {8,9}   hb1 {12,13}
    //  pw01: hb0 {2,3}  hb1 {6,7}    pw11: hb0 {10,11} hb1 {14,15}
    // ISA: swap(dst,src): new_dst[32:63]=old_src[0:31]; new_src[0:31]=old_dst[32:63].
    // r = swap(pwLOW, pwHIGH): r[0] = word0 (own-low / other-low),
    //                          r[1] = word2 (other-high / own-high).
    short8v pa[4];
#pragma unroll
    for (int kb = 0; kb < 2; ++kb) {
      u32 pw00, pw01, pw10, pw11, pw20, pw21, pw30, pw31;
      asm("v_cvt_pk_bf16_f32 %0, %1, %2" : "=v"(pw00) : "v"(sacc[kb][0]), "v"(sacc[kb][1]));
      asm("v_cvt_pk_bf16_f32 %0, %1, %2" : "=v"(pw01) : "v"(sacc[kb][2]), "v"(sacc[kb][3]));
      asm("v_cvt_pk_bf16_f32 %0, %1, %2" : "=v"(pw10) : "v"(sacc[kb][4]), "v"(sacc[kb][5]));
      asm("v_cvt_pk_bf16_f32 %0, %1, %2" : "=v"(pw11) : "v"(sacc[kb][6]), "v"(sacc[kb][7]));
      asm("v_cvt_pk_bf16_f32 %0, %1, %2" : "=v"(pw20) : "v"(sacc[kb][8]), "v"(sacc[kb][9]));
      asm("v_cvt_pk_bf16_f32 %0, %1, %2" : "=v"(pw21) : "v"(sacc[kb][10]), "v"(sacc[kb][11]));
      asm("v_cvt_pk_bf16_f32 %0, %1, %2" : "=v"(pw30) : "v"(sacc[kb][12]), "v"(sacc[kb][13]));
      asm("v_cvt_pk_bf16_f32 %0, %1, %2" : "=v"(pw31) : "v"(sacc[kb][14]), "v"(sacc[kb][15]));
      u32x2 a0 = __builtin_amdgcn_permlane32_swap(pw00, pw10, false, false);
      u32x2 a1 = __builtin_amdgcn_permlane32_swap(pw01, pw11, false, false);
      u32x4 wv0; wv0[0] = a0[0]; wv0[1] = a1[0]; wv0[2] = a0[1]; wv0[3] = a1[1];
      pa[kb * 2 + 0] = __builtin_bit_cast(short8v, wv0);
      u32x2 b0 = __builtin_amdgcn_permlane32_swap(pw20, pw30, false, false);
      u32x2 b1 = __builtin_amdgcn_permlane32_swap(pw21, pw31, false, false);
      u32x4 wv1; wv1[0] = b0[0]; wv1[1] = b1[0]; wv1[2] = b0[1]; wv1[3] = b1[1];
      pa[kb * 2 + 1] = __builtin_bit_cast(short8v, wv1);
    }

    // PV: O^T[d][q] += V^T[d][s] * P^T[s][q]
    __builtin_amdgcn_s_setprio(1);
#pragma unroll
    for (int sc = 0; sc < 4; ++sc) {
      const int c = sc * 2 + hb;
#pragma unroll
      for (int db = 0; db < 4; ++db) {
        int vr = db * 32 + l31;
        short8v vf = *(const short8v*)(lVc + vr * 128 + ((c ^ (vr & 7)) << 4));
        oacc[db] = __builtin_amdgcn_mfma_f32_32x32x16_bf16(vf, pa[sc],
                                                           oacc[db], 0, 0, 0);
      }
    }
    __builtin_amdgcn_s_setprio(0);

    __syncthreads();
  }

  // epilogue: lane-local normalize, pack pairs, store 8B chunks
  const float inv = 1.0f / l_run;
  u16* yp = Y + ((size_t)b * 2048 + qrow) * 2048 + h * 128;
#pragma unroll
  for (int db = 0; db < 4; ++db)
#pragma unroll
    for (int j = 0; j < 4; ++j) {
      float a0 = oacc[db][4 * j] * inv, a1 = oacc[db][4 * j + 1] * inv;
      float a2 = oacc[db][4 * j + 2] * inv, a3 = oacc[db][4 * j + 3] * inv;
      u32 w0, w1;
      asm("v_cvt_pk_bf16_f32 %0, %1, %2" : "=v"(w0) : "v"(a0), "v"(a1));
      asm("v_cvt_pk_bf16_f32 %0, %1, %2" : "=v"(w1) : "v"(a2), "v"(a3));
      *(u32x2*)(yp + db * 32 + 8 * j + 4 * hb) = (u32x2){w0, w1};
    }
}

// ---------------- RMSNorm ----------------
__global__ __launch_bounds__(256) void rmsnorm_k(const u16* __restrict__ Yb,
                                                 const float* __restrict__ nw,
                                                 float* __restrict__ out) {
  const int row = blockIdx.x;
  const int t = threadIdx.x;
  const u16* yr = Yb + (size_t)row * 2048 + t * 8;
  short8v v = *(const short8v*)yr;
  float x[8];
  float ss = 0.f;
#pragma unroll
  for (int j = 0; j < 8; ++j) {
    x[j] = b2f((u16)v[j]);
    ss += x[j] * x[j];
  }
#pragma unroll
  for (int dm = 1; dm < 64; dm <<= 1) ss += __shfl_xor(ss, dm, 64);
  __shared__ float red[4];
  if ((t & 63) == 0) red[t >> 6] = ss;
  __syncthreads();
  float tot = red[0] + red[1] + red[2] + red[3];
  float inv = rsqrtf(tot * (1.0f / 2048.0f) + 1e-6f);
  float* op = out + (size_t)row * 2048 + t * 8;
  const float* wp = nw + t * 8;
  f32x4 o0, o1;
#pragma unroll
  for (int j = 0; j < 4; ++j) o0[j] = x[j] * inv * wp[j];
#pragma unroll
  for (int j = 0; j < 4; ++j) o1[j] = x[4 + j] * inv * wp[4 + j];
  *(f32x4*)op = o0;
  *(f32x4*)(op + 4) = o1;
}

extern "C" void kernel_launch(void* const* d_in, const int* in_sizes, int n_in,
                              void* d_out, int out_size, void* d_ws,
                              size_t ws_size, hipStream_t stream) {
  (void)in_sizes; (void)n_in; (void)out_size; (void)ws_size;
  const float* x = (const float*)d_in[0];
  const float* w_attn = (const float*)d_in[1];
  const float* w_proj = (const float*)d_in[2];
  const float* norm_w = (const float*)d_in[3];
  float* out = (float*)d_out;
  char* ws = (char*)d_ws;

  size_t off = 0;
  auto alloc = [&](size_t n) {
    size_t r = off;
    off += (n + 255) & ~(size_t)255;
    return r;
  };
  u16* xb = (u16*)(ws + alloc(33554432));     // x bf16 [8192][2048]
  u16* wabT = (u16*)(ws + alloc(12582912));   // w_attn^T bf16 [3072][2048]
  u16* qkv = (u16*)(ws + alloc(50331648));    // [8192][3072]
  u16* q_r = (u16*)(ws + alloc(33554432));    // [4][16][2048][128]
  u16* vT = (u16*)(ws + alloc(8388608));      // [4][4][128][2048]
  u16* wpT = (u16*)(ws + alloc(8388608));     // w_proj^T bf16 [2048][2048]
  float* cosT = (float*)(ws + alloc(524288)); // [2048][64]
  float* sinT = (float*)(ws + alloc(524288));
  u16* k_r = wabT;  // reuse (dead after GEMM1)
  u16* y = xb;      // reuse: attn out [8192][2048]
  u16* y2 = qkv;    // reuse: proj out [8192][2048]

  cvt_x_k<<<8192, 256, 0, stream>>>(x, xb);
  transpose_cvt_k<<<dim3(48, 32), 256, 0, stream>>>(w_attn, wabT, 2048, 3072);
  transpose_cvt_k<<<dim3(32, 32), 256, 0, stream>>>(w_proj, wpT, 2048, 2048);
  rope_table_k<<<512, 256, 0, stream>>>(cosT, sinT);
  gemm256_k<<<dim3(12, 32), 512, 0, stream>>>(xb, wabT, qkv, 3072, 2048);
  rope_scatter_k<<<8192, 256, 0, stream>>>(qkv, cosT, sinT, q_r, k_r);
  v_trans_k<<<dim3(32, 2, 16), 256, 0, stream>>>(qkv, vT);
  attn_k<<<dim3(1024), 256, 0, stream>>>(q_r, k_r, vT, y);
  gemm256_k<<<dim3(8, 32), 512, 0, stream>>>(y, wpT, y2, 2048, 2048);
  rmsnorm_k<<<8192, 256, 0, stream>>>(y2, norm_w, out);
}